// Round 9
// baseline (354.108 us; speedup 1.0000x reference)
//
#include <hip/hip_runtime.h>

namespace {
constexpr int kB = 8;
constexpr int kC = 64;
constexpr int kN = 100000;
constexpr int kR = 32;
constexpr int kR3 = kR * kR * kR;                     // 32768
constexpr size_t kGridElems = (size_t)kB * kC * kR3;  // 16,777,216
constexpr int kNV = kB * kR3;                         // 262144 voxel bins
constexpr int kNQ = kNV / 4;                          // 65536 voxel quads

// ws layout (bytes)
constexpr size_t kDsumOff = 0;                                 // 192 B
constexpr size_t kMaxOff = 192;                                // 32 B
constexpr size_t kNqOff = 240;                                 // 4 B quad counter
constexpr size_t kBsumOff = 1024;                              // 1 KB (256 uint)
constexpr size_t kCountsOff = 4096;                            // 1 MB (reused as qlist)
constexpr size_t kOffsetsOff = kCountsOff + (size_t)kNV * 4;   // (kNV+1) uints
constexpr size_t kHashOff = kOffsetsOff + (size_t)(kNV + 64) * 4;  // u16 x 800000
constexpr size_t kLrOff = kHashOff + (size_t)kB * kN * 2;      // u32 x 800000
constexpr size_t kFeatTOff = kLrOff + (size_t)kB * kN * 4;
inline size_t wsNeed(int chunkB) { return kFeatTOff + (size_t)chunkB * kN * kC * 4; }
}  // namespace

__device__ __forceinline__ void f4add(float4& a, const float4& f) {
  a.x += f.x; a.y += f.y; a.z += f.z; a.w += f.w;
}
__device__ __forceinline__ void f4red(float4& a) {
  a.x += __shfl_xor(a.x, 16); a.y += __shfl_xor(a.y, 16);
  a.z += __shfl_xor(a.z, 16); a.w += __shfl_xor(a.w, 16);
  a.x += __shfl_xor(a.x, 32); a.y += __shfl_xor(a.y, 32);
  a.z += __shfl_xor(a.z, 32); a.w += __shfl_xor(a.w, 32);
}

// ---------------- Kernel A: per-batch coordinate sums (double) ----------------
__global__ __launch_bounds__(256) void mean_kernel(const float* __restrict__ coords,
                                                   double* __restrict__ dsum) {
  const int b = blockIdx.y;
  const int tid = blockIdx.x * blockDim.x + threadIdx.x;
  const int stride = gridDim.x * blockDim.x;
  const float* cb = coords + (size_t)b * 3 * kN;
  double s0 = 0.0, s1 = 0.0, s2 = 0.0;
  for (int n = tid; n < kN; n += stride) {
    s0 += (double)cb[n];
    s1 += (double)cb[kN + n];
    s2 += (double)cb[2 * kN + n];
  }
  __shared__ double sh[3][256];
  sh[0][threadIdx.x] = s0;
  sh[1][threadIdx.x] = s1;
  sh[2][threadIdx.x] = s2;
  __syncthreads();
  for (int off = 128; off > 0; off >>= 1) {
    if (threadIdx.x < (unsigned)off) {
      sh[0][threadIdx.x] += sh[0][threadIdx.x + off];
      sh[1][threadIdx.x] += sh[1][threadIdx.x + off];
      sh[2][threadIdx.x] += sh[2][threadIdx.x + off];
    }
    __syncthreads();
  }
  if (threadIdx.x == 0) {
    atomicAdd(&dsum[b * 3 + 0], sh[0][0]);
    atomicAdd(&dsum[b * 3 + 1], sh[1][0]);
    atomicAdd(&dsum[b * 3 + 2], sh[2][0]);
  }
}

// ------------- Kernel B: per-batch max of squared norm (f32, no fma) ----------
__global__ __launch_bounds__(256) void maxnorm_kernel(const float* __restrict__ coords,
                                                      const double* __restrict__ dsum,
                                                      unsigned* __restrict__ maxbits) {
#pragma clang fp contract(off)
  const int b = blockIdx.y;
  const int tid = blockIdx.x * blockDim.x + threadIdx.x;
  const int stride = gridDim.x * blockDim.x;
  const float* cb = coords + (size_t)b * 3 * kN;
  const float m0 = (float)(dsum[b * 3 + 0] / (double)kN);
  const float m1 = (float)(dsum[b * 3 + 1] / (double)kN);
  const float m2 = (float)(dsum[b * 3 + 2] / (double)kN);
  float mx = 0.0f;
  for (int n = tid; n < kN; n += stride) {
    float x = cb[n] - m0;
    float y = cb[kN + n] - m1;
    float z = cb[2 * kN + n] - m2;
    float sx = x * x;
    float sy = y * y;
    float sz = z * z;
    float s = (sx + sy) + sz;  // match numpy's non-fused order
    mx = fmaxf(mx, s);
  }
  __shared__ float sh[256];
  sh[threadIdx.x] = mx;
  __syncthreads();
  for (int off = 128; off > 0; off >>= 1) {
    if (threadIdx.x < (unsigned)off)
      sh[threadIdx.x] = fmaxf(sh[threadIdx.x], sh[threadIdx.x + off]);
    __syncthreads();
  }
  if (threadIdx.x == 0) atomicMax(&maxbits[b], __float_as_uint(sh[0]));
}

// ---------- common per-point geometry: returns h[4], writes norm_coords ------
__device__ __forceinline__ void point_geom(const float* __restrict__ coords,
                                           const double* __restrict__ dsum,
                                           const unsigned* __restrict__ maxbits,
                                           float* __restrict__ out_nc, int b, int n0,
                                           int h[4]) {
#pragma clang fp contract(off)
  const float m0 = (float)(dsum[b * 3 + 0] / (double)kN);
  const float m1 = (float)(dsum[b * 3 + 1] / (double)kN);
  const float m2 = (float)(dsum[b * 3 + 2] / (double)kN);
  const float scale = 2.0f * sqrtf(__uint_as_float(maxbits[b]));

  const float* cb = coords + (size_t)b * 3 * kN;
  const float4 cx = *(const float4*)(cb + n0);
  const float4 cy = *(const float4*)(cb + kN + n0);
  const float4 cz = *(const float4*)(cb + 2 * kN + n0);

  float xa[4] = {cx.x, cx.y, cx.z, cx.w};
  float ya[4] = {cy.x, cy.y, cy.z, cy.w};
  float za[4] = {cz.x, cz.y, cz.z, cz.w};
  float vx[4], vy[4], vz[4];
#pragma unroll
  for (int k = 0; k < 4; ++k) {
    float tx = (xa[k] - m0) / scale + 0.5f;
    float ty = (ya[k] - m1) / scale + 0.5f;
    float tz = (za[k] - m2) / scale + 0.5f;
    vx[k] = fminf(fmaxf(tx * 32.0f, 0.0f), 31.0f);
    vy[k] = fminf(fmaxf(ty * 32.0f, 0.0f), 31.0f);
    vz[k] = fminf(fmaxf(tz * 32.0f, 0.0f), 31.0f);
    int ix = (int)rintf(vx[k]);
    int iy = (int)rintf(vy[k]);
    int iz = (int)rintf(vz[k]);
    h[k] = ix * (kR * kR) + iy * kR + iz;
  }
  float* nb = out_nc + (size_t)b * 3 * kN;
  *(float4*)(nb + n0) = make_float4(vx[0], vx[1], vx[2], vx[3]);
  *(float4*)(nb + kN + n0) = make_float4(vy[0], vy[1], vy[2], vy[3]);
  *(float4*)(nb + 2 * kN + n0) = make_float4(vz[0], vz[1], vz[2], vz[3]);
}

// - Kernel C: hash + nc + count histogram + local rank (800k uint atomics) ----
__global__ __launch_bounds__(256) void hash_nc_kernel(
    const float* __restrict__ coords, const double* __restrict__ dsum,
    const unsigned* __restrict__ maxbits, float* __restrict__ out_nc,
    unsigned short* __restrict__ hashes, unsigned* __restrict__ lr,
    unsigned* __restrict__ counts) {
  const int b = blockIdx.y;
  const int n0 = (blockIdx.x * 256 + threadIdx.x) * 4;
  if (n0 >= kN) return;
  int h[4];
  point_geom(coords, dsum, maxbits, out_nc, b, n0, h);
  ushort4 h4;
  h4.x = (unsigned short)h[0];
  h4.y = (unsigned short)h[1];
  h4.z = (unsigned short)h[2];
  h4.w = (unsigned short)h[3];
  *(ushort4*)(hashes + (size_t)b * kN + n0) = h4;
  unsigned* cnt = counts + (size_t)b * kR3;
  uint4 l;
  l.x = atomicAdd(&cnt[h[0]], 1u);
  l.y = atomicAdd(&cnt[h[1]], 1u);
  l.z = atomicAdd(&cnt[h[2]], 1u);
  l.w = atomicAdd(&cnt[h[3]], 1u);
  *(uint4*)(lr + (size_t)b * kN + n0) = l;
}

// --------------------------- scan (3 kernels) --------------------------------
__global__ __launch_bounds__(256) void scan_reduce(const unsigned* __restrict__ counts,
                                                   unsigned* __restrict__ bsum) {
  __shared__ unsigned sh[256];
  const int t = threadIdx.x;
  const uint4 c = ((const uint4*)counts)[blockIdx.x * 256 + t];
  sh[t] = c.x + c.y + c.z + c.w;
  __syncthreads();
  for (int off = 128; off > 0; off >>= 1) {
    if (t < off) sh[t] += sh[t + off];
    __syncthreads();
  }
  if (t == 0) bsum[blockIdx.x] = sh[0];
}

__global__ __launch_bounds__(256) void scan_bsum(unsigned* __restrict__ bsum) {
  __shared__ unsigned sh[256];
  const int t = threadIdx.x;
  const unsigned v = bsum[t];
  sh[t] = v;
  __syncthreads();
  for (int d = 1; d < 256; d <<= 1) {
    const unsigned x = (t >= d) ? sh[t - d] : 0u;
    __syncthreads();
    sh[t] += x;
    __syncthreads();
  }
  bsum[t] = sh[t] - v;  // exclusive
}

__global__ __launch_bounds__(256) void scan_write(const unsigned* __restrict__ counts,
                                                  const unsigned* __restrict__ bsum,
                                                  unsigned* __restrict__ offsets) {
  __shared__ unsigned sh[256];
  const int t = threadIdx.x;
  const int gi = blockIdx.x * 256 + t;
  const uint4 c = ((const uint4*)counts)[gi];
  const unsigned tot = c.x + c.y + c.z + c.w;
  sh[t] = tot;
  __syncthreads();
  for (int d = 1; d < 256; d <<= 1) {
    const unsigned x = (t >= d) ? sh[t - d] : 0u;
    __syncthreads();
    sh[t] += x;
    __syncthreads();
  }
  const unsigned base = bsum[blockIdx.x] + sh[t] - tot;
  uint4 o;
  o.x = base;
  o.y = o.x + c.x;
  o.z = o.y + c.y;
  o.w = o.z + c.z;
  ((uint4*)offsets)[gi] = o;
  if (gi == kNV / 4 - 1) offsets[kNV] = o.w + c.w;  // total = B*N
}

// ------ Kernel D: compact occupied voxel-quads into qlist (counts region) ----
__global__ __launch_bounds__(256) void compact_kernel(const unsigned* __restrict__ offsets,
                                                      unsigned* __restrict__ qlist,
                                                      unsigned* __restrict__ nq) {
  const int q = blockIdx.x * 256 + threadIdx.x;
  if (q >= kNQ) return;
  if (offsets[q * 4 + 4] > offsets[q * 4]) {
    const unsigned i = atomicAdd(nq, 1u);
    qlist[i] = (unsigned)q;
  }
}

// --- Kernel F: transpose feat (B,C,N) -> SORTED rows feat_t[off[h]+lr][c] ----
__global__ __launch_bounds__(256) void tr_kernel(const float* __restrict__ feat,
                                                 const unsigned short* __restrict__ hashes,
                                                 const unsigned* __restrict__ lr,
                                                 const unsigned* __restrict__ offsets,
                                                 float* __restrict__ feat_t, int b0) {
  const int b2 = blockIdx.y;
  const int b = b0 + b2;
  const int n0 = blockIdx.x * 32;
  __shared__ float tile[64][33];
  __shared__ unsigned shr[32];
  if (threadIdx.x < 32) {
    const int n = n0 + threadIdx.x;
    const unsigned hh = hashes[(size_t)b * kN + n];
    const unsigned l = lr[(size_t)b * kN + n];
    shr[threadIdx.x] = offsets[(size_t)b * kR3 + hh] + l - (unsigned)b0 * (unsigned)kN;
  }
  const float* fb = feat + (size_t)b * kC * kN;
#pragma unroll
  for (int j = 0; j < 2; ++j) {
    const int idx = j * 256 + threadIdx.x;  // 0..511
    const int c = idx >> 3;
    const int q = idx & 7;
    const float4 v = *(const float4*)(fb + (size_t)c * kN + n0 + q * 4);
    tile[c][q * 4 + 0] = v.x;
    tile[c][q * 4 + 1] = v.y;
    tile[c][q * 4 + 2] = v.z;
    tile[c][q * 4 + 3] = v.w;
  }
  __syncthreads();
#pragma unroll
  for (int j = 0; j < 2; ++j) {
    const int idx = j * 256 + threadIdx.x;  // 0..511
    const int n = idx >> 4;
    const int cq = idx & 15;
    float4 w;
    w.x = tile[cq * 4 + 0][n];
    w.y = tile[cq * 4 + 1][n];
    w.z = tile[cq * 4 + 2][n];
    w.w = tile[cq * 4 + 3][n];
    const size_t row = (size_t)shr[n];
    *(float4*)(feat_t + row * kC + cq * 4) = w;
  }
}

// --- Kernel G: grid-stride over COMPACTED occupied quads; direct stores ------
__global__ __launch_bounds__(256) void gather_kernel(const float* __restrict__ feat_t,
                                                     const unsigned* __restrict__ offsets,
                                                     const unsigned* __restrict__ qlist,
                                                     const unsigned* __restrict__ nq,
                                                     float* __restrict__ out, int b0,
                                                     int chunkB) {
  const unsigned nquads = *nq;
  const int nWaves = gridDim.x * 4;
  const int wid = blockIdx.x * 4 + (threadIdx.x >> 6);
  const int lane = threadIdx.x & 63;
  const int p = lane >> 4;   // row slot / component select, 0..3
  const int cq = lane & 15;  // channel quad 0..15
  const unsigned rb = (unsigned)b0 * (unsigned)kN;
  const int qlo = b0 * (kR3 / 4);
  const int qhi = (b0 + chunkB) * (kR3 / 4);

  for (unsigned qi = (unsigned)wid; qi < nquads; qi += (unsigned)nWaves) {
    const int q = (int)qlist[qi];
    if (q < qlo || q >= qhi) continue;  // not in this chunk
    const int vgl = q * 4;              // global voxel index (4-aligned)
    const int b = vgl >> 15;            // batch
    const int h0 = vgl & (kR3 - 1);

    const uint4 o4 = *(const uint4*)(offsets + vgl);
    const unsigned e3 = offsets[vgl + 4];
    const unsigned s0 = o4.x, e0 = o4.y, e1 = o4.z, e2 = o4.w;

    float4 a0 = make_float4(0.f, 0.f, 0.f, 0.f);
    float4 a1 = make_float4(0.f, 0.f, 0.f, 0.f);
    float4 a2 = make_float4(0.f, 0.f, 0.f, 0.f);
    float4 a3 = make_float4(0.f, 0.f, 0.f, 0.f);
    for (unsigned r = s0 + (unsigned)p; r < e3; r += 4) {
      const float4 f = *(const float4*)(feat_t + (size_t)(r - rb) * kC + cq * 4);
      if (r < e0)      f4add(a0, f);
      else if (r < e1) f4add(a1, f);
      else if (r < e2) f4add(a2, f);
      else             f4add(a3, f);
    }
    f4red(a0);
    f4red(a1);
    f4red(a2);
    f4red(a3);
    const float k0 = (e0 > s0) ? (float)(e0 - s0) : 1.0f;
    const float k1 = (e1 > e0) ? (float)(e1 - e0) : 1.0f;
    const float k2 = (e2 > e1) ? (float)(e2 - e1) : 1.0f;
    const float k3 = (e3 > e2) ? (float)(e3 - e2) : 1.0f;
    const float w0 = (p == 0) ? a0.x : (p == 1) ? a0.y : (p == 2) ? a0.z : a0.w;
    const float w1 = (p == 0) ? a1.x : (p == 1) ? a1.y : (p == 2) ? a1.z : a1.w;
    const float w2 = (p == 0) ? a2.x : (p == 1) ? a2.y : (p == 2) ? a2.z : a2.w;
    const float w3 = (p == 0) ? a3.x : (p == 1) ? a3.y : (p == 2) ? a3.z : a3.w;
    float* ob = out + ((size_t)b * kC + (cq * 4 + p)) * kR3 + h0;
    *(float4*)ob = make_float4(w0 / k0, w1 / k1, w2 / k2, w3 / k3);
  }
}

// --------------- Fallback: direct atomics into out (b,c,h) -------------------
__global__ __launch_bounds__(256) void scatter_direct(
    const float* __restrict__ feat, const float* __restrict__ coords,
    const double* __restrict__ dsum, const unsigned* __restrict__ maxbits,
    float* __restrict__ gridsum, float* __restrict__ out_nc,
    unsigned* __restrict__ counts) {
  const int b = blockIdx.y;
  const int n0 = (blockIdx.x * 256 + threadIdx.x) * 4;
  if (n0 >= kN) return;
  int h[4];
  point_geom(coords, dsum, maxbits, out_nc, b, n0, h);
  unsigned* cnt = counts + (size_t)b * kR3;
  atomicAdd(&cnt[h[0]], 1u);
  atomicAdd(&cnt[h[1]], 1u);
  atomicAdd(&cnt[h[2]], 1u);
  atomicAdd(&cnt[h[3]], 1u);
  const float* fb = feat + (size_t)b * kC * kN + n0;
  float* gb = gridsum + (size_t)b * kC * kR3;
#pragma unroll 8
  for (int c = 0; c < kC; ++c) {
    const float4 f = *(const float4*)(fb + (size_t)c * kN);
    float* g = gb + (size_t)c * kR3;
    unsafeAtomicAdd(g + h[0], f.x);
    unsafeAtomicAdd(g + h[1], f.y);
    unsafeAtomicAdd(g + h[2], f.z);
    unsafeAtomicAdd(g + h[3], f.w);
  }
}

__global__ __launch_bounds__(256) void divide_inplace(float* __restrict__ grid,
                                                      const unsigned* __restrict__ counts) {
  const size_t e = ((size_t)blockIdx.x * blockDim.x + threadIdx.x) * 4;
  if (e >= kGridElems) return;
  const int h = (int)(e & (size_t)(kR3 - 1));
  const int b = (int)(e >> 21);
  const uint4 cnt = *(const uint4*)(counts + (size_t)b * kR3 + h);
  float4 g = *(float4*)(grid + e);
  g.x = g.x / (float)(cnt.x > 1u ? cnt.x : 1u);
  g.y = g.y / (float)(cnt.y > 1u ? cnt.y : 1u);
  g.z = g.z / (float)(cnt.z > 1u ? cnt.z : 1u);
  g.w = g.w / (float)(cnt.w > 1u ? cnt.w : 1u);
  *(float4*)(grid + e) = g;
}

extern "C" void kernel_launch(void* const* d_in, const int* in_sizes, int n_in,
                              void* d_out, int out_size, void* d_ws, size_t ws_size,
                              hipStream_t stream) {
  const float* feat = (const float*)d_in[0];    // (8, 64, 100000)
  const float* coords = (const float*)d_in[1];  // (8, 3, 100000)
  float* out = (float*)d_out;
  float* out_nc = out + kGridElems;  // (8, 3, 100000)

  char* ws = (char*)d_ws;
  double* dsum = (double*)(ws + kDsumOff);
  unsigned* maxbits = (unsigned*)(ws + kMaxOff);
  unsigned* nq = (unsigned*)(ws + kNqOff);
  unsigned* bsum = (unsigned*)(ws + kBsumOff);
  unsigned* counts = (unsigned*)(ws + kCountsOff);
  unsigned* qlist = counts;  // counts region reused after scan_write
  unsigned* offsets = (unsigned*)(ws + kOffsetsOff);
  unsigned short* hashes = (unsigned short*)(ws + kHashOff);
  unsigned* lr = (unsigned*)(ws + kLrOff);
  float* feat_t = (float*)(ws + kFeatTOff);

  const dim3 blk(256);
  const int pblk = (kN / 4 + 255) / 256;  // 98 point-blocks per batch

  // zero header (incl. nq) + counts (rest is fully rewritten each call)
  hipMemsetAsync(ws, 0, kCountsOff + (size_t)kNV * sizeof(unsigned), stream);

  mean_kernel<<<dim3(32, kB), blk, 0, stream>>>(coords, dsum);
  maxnorm_kernel<<<dim3(32, kB), blk, 0, stream>>>(coords, dsum, maxbits);

  int chunkB = 0;
  for (int c = kB; c >= 1; c >>= 1) {
    if (ws_size >= wsNeed(c)) { chunkB = c; break; }
  }

  if (chunkB) {
    hash_nc_kernel<<<dim3(pblk, kB), blk, 0, stream>>>(coords, dsum, maxbits, out_nc,
                                                       hashes, lr, counts);
    scan_reduce<<<dim3(256), blk, 0, stream>>>(counts, bsum);
    scan_bsum<<<dim3(1), blk, 0, stream>>>(bsum);
    scan_write<<<dim3(256), blk, 0, stream>>>(counts, bsum, offsets);
    compact_kernel<<<dim3(kNQ / 256), blk, 0, stream>>>(offsets, qlist, nq);

    // zeros for empty voxels come from this fill; gather writes occupied only
    hipMemsetAsync(out, 0, kGridElems * sizeof(float), stream);

    for (int b0 = 0; b0 < kB; b0 += chunkB) {
      tr_kernel<<<dim3(kN / 32, chunkB), blk, 0, stream>>>(feat, hashes, lr, offsets,
                                                           feat_t, b0);
      gather_kernel<<<dim3(2048), blk, 0, stream>>>(feat_t, offsets, qlist, nq, out, b0,
                                                    chunkB);
    }
  } else {
    // fallback: direct atomics into final layout
    hipMemsetAsync(out, 0, kGridElems * sizeof(float), stream);
    scatter_direct<<<dim3(pblk, kB), blk, 0, stream>>>(feat, coords, dsum, maxbits, out,
                                                       out_nc, counts);
    const size_t vec4 = kGridElems / 4;
    divide_inplace<<<dim3((unsigned)((vec4 + 255) / 256)), blk, 0, stream>>>(out, counts);
  }
}

// Round 10
// 251.739 us; speedup vs baseline: 1.4066x; 1.4066x over previous
//
#include <hip/hip_runtime.h>

namespace {
constexpr int kB = 8;
constexpr int kC = 64;
constexpr int kN = 100000;
constexpr int kR = 32;
constexpr int kR3 = kR * kR * kR;                     // 32768
constexpr size_t kGridElems = (size_t)kB * kC * kR3;  // 16,777,216
constexpr int kNV = kB * kR3;                         // 262144 voxel bins
constexpr int kNQ = kNV / 4;                          // 65536
constexpr unsigned kTh = 32;                          // light/heavy row threshold
constexpr int kMaxHeavy = kB * kN / (int)(kTh + 1) + 2;  // <= 24244

// ws layout (bytes)
constexpr size_t kDsumOff = 0;                                 // 192 B
constexpr size_t kMaxOff = 192;                                // 32 B
constexpr size_t kNlhOff = 240;                                // 2 uints
constexpr size_t kBsumOff = 1024;                              // u32[256]
constexpr size_t kBsum2Off = 2048;                             // uint2[256]
constexpr size_t kCountsOff = 4096;                            // 1 MB (reused as Llist)
constexpr size_t kOffsetsOff = kCountsOff + (size_t)kNV * 4;   // (kNV+64) uints
constexpr size_t kHlistOff = kOffsetsOff + (size_t)(kNV + 64) * 4;  // u32 x kNQ
constexpr size_t kHashOff = kHlistOff + (size_t)kNQ * 4;       // u16 x 800000
constexpr size_t kLrOff = kHashOff + (size_t)kB * kN * 2;      // u32 x 800000
constexpr size_t kFeatTOff = kLrOff + (size_t)kB * kN * 4;
inline size_t wsNeed(int chunkB) { return kFeatTOff + (size_t)chunkB * kN * kC * 4; }
}  // namespace

__device__ __forceinline__ void f4add(float4& a, const float4& f) {
  a.x += f.x; a.y += f.y; a.z += f.z; a.w += f.w;
}

// ---------------- Kernel A: per-batch coordinate sums (double) ----------------
__global__ __launch_bounds__(256) void mean_kernel(const float* __restrict__ coords,
                                                   double* __restrict__ dsum) {
  const int b = blockIdx.y;
  const int tid = blockIdx.x * blockDim.x + threadIdx.x;
  const int stride = gridDim.x * blockDim.x;
  const float* cb = coords + (size_t)b * 3 * kN;
  double s0 = 0.0, s1 = 0.0, s2 = 0.0;
  for (int n = tid; n < kN; n += stride) {
    s0 += (double)cb[n];
    s1 += (double)cb[kN + n];
    s2 += (double)cb[2 * kN + n];
  }
  __shared__ double sh[3][256];
  sh[0][threadIdx.x] = s0;
  sh[1][threadIdx.x] = s1;
  sh[2][threadIdx.x] = s2;
  __syncthreads();
  for (int off = 128; off > 0; off >>= 1) {
    if (threadIdx.x < (unsigned)off) {
      sh[0][threadIdx.x] += sh[0][threadIdx.x + off];
      sh[1][threadIdx.x] += sh[1][threadIdx.x + off];
      sh[2][threadIdx.x] += sh[2][threadIdx.x + off];
    }
    __syncthreads();
  }
  if (threadIdx.x == 0) {
    atomicAdd(&dsum[b * 3 + 0], sh[0][0]);
    atomicAdd(&dsum[b * 3 + 1], sh[1][0]);
    atomicAdd(&dsum[b * 3 + 2], sh[2][0]);
  }
}

// ------------- Kernel B: per-batch max of squared norm (f32, no fma) ----------
__global__ __launch_bounds__(256) void maxnorm_kernel(const float* __restrict__ coords,
                                                      const double* __restrict__ dsum,
                                                      unsigned* __restrict__ maxbits) {
#pragma clang fp contract(off)
  const int b = blockIdx.y;
  const int tid = blockIdx.x * blockDim.x + threadIdx.x;
  const int stride = gridDim.x * blockDim.x;
  const float* cb = coords + (size_t)b * 3 * kN;
  const float m0 = (float)(dsum[b * 3 + 0] / (double)kN);
  const float m1 = (float)(dsum[b * 3 + 1] / (double)kN);
  const float m2 = (float)(dsum[b * 3 + 2] / (double)kN);
  float mx = 0.0f;
  for (int n = tid; n < kN; n += stride) {
    float x = cb[n] - m0;
    float y = cb[kN + n] - m1;
    float z = cb[2 * kN + n] - m2;
    float sx = x * x;
    float sy = y * y;
    float sz = z * z;
    float s = (sx + sy) + sz;  // match numpy's non-fused order
    mx = fmaxf(mx, s);
  }
  __shared__ float sh[256];
  sh[threadIdx.x] = mx;
  __syncthreads();
  for (int off = 128; off > 0; off >>= 1) {
    if (threadIdx.x < (unsigned)off)
      sh[threadIdx.x] = fmaxf(sh[threadIdx.x], sh[threadIdx.x + off]);
    __syncthreads();
  }
  if (threadIdx.x == 0) atomicMax(&maxbits[b], __float_as_uint(sh[0]));
}

// ---------- common per-point geometry: returns h[4], writes norm_coords ------
__device__ __forceinline__ void point_geom(const float* __restrict__ coords,
                                           const double* __restrict__ dsum,
                                           const unsigned* __restrict__ maxbits,
                                           float* __restrict__ out_nc, int b, int n0,
                                           int h[4]) {
#pragma clang fp contract(off)
  const float m0 = (float)(dsum[b * 3 + 0] / (double)kN);
  const float m1 = (float)(dsum[b * 3 + 1] / (double)kN);
  const float m2 = (float)(dsum[b * 3 + 2] / (double)kN);
  const float scale = 2.0f * sqrtf(__uint_as_float(maxbits[b]));

  const float* cb = coords + (size_t)b * 3 * kN;
  const float4 cx = *(const float4*)(cb + n0);
  const float4 cy = *(const float4*)(cb + kN + n0);
  const float4 cz = *(const float4*)(cb + 2 * kN + n0);

  float xa[4] = {cx.x, cx.y, cx.z, cx.w};
  float ya[4] = {cy.x, cy.y, cy.z, cy.w};
  float za[4] = {cz.x, cz.y, cz.z, cz.w};
  float vx[4], vy[4], vz[4];
#pragma unroll
  for (int k = 0; k < 4; ++k) {
    float tx = (xa[k] - m0) / scale + 0.5f;
    float ty = (ya[k] - m1) / scale + 0.5f;
    float tz = (za[k] - m2) / scale + 0.5f;
    vx[k] = fminf(fmaxf(tx * 32.0f, 0.0f), 31.0f);
    vy[k] = fminf(fmaxf(ty * 32.0f, 0.0f), 31.0f);
    vz[k] = fminf(fmaxf(tz * 32.0f, 0.0f), 31.0f);
    int ix = (int)rintf(vx[k]);
    int iy = (int)rintf(vy[k]);
    int iz = (int)rintf(vz[k]);
    h[k] = ix * (kR * kR) + iy * kR + iz;
  }
  float* nb = out_nc + (size_t)b * 3 * kN;
  *(float4*)(nb + n0) = make_float4(vx[0], vx[1], vx[2], vx[3]);
  *(float4*)(nb + kN + n0) = make_float4(vy[0], vy[1], vy[2], vy[3]);
  *(float4*)(nb + 2 * kN + n0) = make_float4(vz[0], vz[1], vz[2], vz[3]);
}

// - Kernel C: hash + nc + count histogram + local rank (800k uint atomics) ----
__global__ __launch_bounds__(256) void hash_nc_kernel(
    const float* __restrict__ coords, const double* __restrict__ dsum,
    const unsigned* __restrict__ maxbits, float* __restrict__ out_nc,
    unsigned short* __restrict__ hashes, unsigned* __restrict__ lr,
    unsigned* __restrict__ counts) {
  const int b = blockIdx.y;
  const int n0 = (blockIdx.x * 256 + threadIdx.x) * 4;
  if (n0 >= kN) return;
  int h[4];
  point_geom(coords, dsum, maxbits, out_nc, b, n0, h);
  ushort4 h4;
  h4.x = (unsigned short)h[0];
  h4.y = (unsigned short)h[1];
  h4.z = (unsigned short)h[2];
  h4.w = (unsigned short)h[3];
  *(ushort4*)(hashes + (size_t)b * kN + n0) = h4;
  unsigned* cnt = counts + (size_t)b * kR3;
  uint4 l;
  l.x = atomicAdd(&cnt[h[0]], 1u);
  l.y = atomicAdd(&cnt[h[1]], 1u);
  l.z = atomicAdd(&cnt[h[2]], 1u);
  l.w = atomicAdd(&cnt[h[3]], 1u);
  *(uint4*)(lr + (size_t)b * kN + n0) = l;
}

// --------------------------- scan (3 kernels) --------------------------------
__global__ __launch_bounds__(256) void scan_reduce(const unsigned* __restrict__ counts,
                                                   unsigned* __restrict__ bsum) {
  __shared__ unsigned sh[256];
  const int t = threadIdx.x;
  const uint4 c = ((const uint4*)counts)[blockIdx.x * 256 + t];
  sh[t] = c.x + c.y + c.z + c.w;
  __syncthreads();
  for (int off = 128; off > 0; off >>= 1) {
    if (t < off) sh[t] += sh[t + off];
    __syncthreads();
  }
  if (t == 0) bsum[blockIdx.x] = sh[0];
}

__global__ __launch_bounds__(256) void scan_bsum(unsigned* __restrict__ bsum) {
  __shared__ unsigned sh[256];
  const int t = threadIdx.x;
  const unsigned v = bsum[t];
  sh[t] = v;
  __syncthreads();
  for (int d = 1; d < 256; d <<= 1) {
    const unsigned x = (t >= d) ? sh[t - d] : 0u;
    __syncthreads();
    sh[t] += x;
    __syncthreads();
  }
  bsum[t] = sh[t] - v;  // exclusive
}

__global__ __launch_bounds__(256) void scan_write(const unsigned* __restrict__ counts,
                                                  const unsigned* __restrict__ bsum,
                                                  unsigned* __restrict__ offsets) {
  __shared__ unsigned sh[256];
  const int t = threadIdx.x;
  const int gi = blockIdx.x * 256 + t;
  const uint4 c = ((const uint4*)counts)[gi];
  const unsigned tot = c.x + c.y + c.z + c.w;
  sh[t] = tot;
  __syncthreads();
  for (int d = 1; d < 256; d <<= 1) {
    const unsigned x = (t >= d) ? sh[t - d] : 0u;
    __syncthreads();
    sh[t] += x;
    __syncthreads();
  }
  const unsigned base = bsum[blockIdx.x] + sh[t] - tot;
  uint4 o;
  o.x = base;
  o.y = o.x + c.x;
  o.z = o.y + c.y;
  o.w = o.z + c.z;
  ((uint4*)offsets)[gi] = o;
  if (gi == kNV / 4 - 1) offsets[kNV] = o.w + c.w;  // total = B*N
}

// --------- dual scan: classify voxels light(1..kTh) / heavy(>kTh) ------------
__global__ __launch_bounds__(256) void dscan_reduce(const unsigned* __restrict__ offsets,
                                                    uint2* __restrict__ bsum2) {
  __shared__ unsigned shl[256], shh[256];
  const int t = threadIdx.x;
  const int v0 = (blockIdx.x * 256 + t) * 4;
  const uint4 o = *(const uint4*)(offsets + v0);
  const unsigned o4 = offsets[v0 + 4];
  const unsigned c0 = o.y - o.x, c1 = o.z - o.y, c2 = o.w - o.z, c3 = o4 - o.w;
  unsigned lt = (c0 >= 1 && c0 <= kTh) + (c1 >= 1 && c1 <= kTh) +
                (c2 >= 1 && c2 <= kTh) + (c3 >= 1 && c3 <= kTh);
  unsigned ht = (c0 > kTh) + (c1 > kTh) + (c2 > kTh) + (c3 > kTh);
  shl[t] = lt;
  shh[t] = ht;
  __syncthreads();
  for (int off = 128; off > 0; off >>= 1) {
    if (t < off) {
      shl[t] += shl[t + off];
      shh[t] += shh[t + off];
    }
    __syncthreads();
  }
  if (t == 0) bsum2[blockIdx.x] = make_uint2(shl[0], shh[0]);
}

__global__ __launch_bounds__(256) void dscan_bsum(uint2* __restrict__ bsum2) {
  __shared__ unsigned shl[256], shh[256];
  const int t = threadIdx.x;
  const uint2 v = bsum2[t];
  shl[t] = v.x;
  shh[t] = v.y;
  __syncthreads();
  for (int d = 1; d < 256; d <<= 1) {
    const unsigned xl = (t >= d) ? shl[t - d] : 0u;
    const unsigned xh = (t >= d) ? shh[t - d] : 0u;
    __syncthreads();
    shl[t] += xl;
    shh[t] += xh;
    __syncthreads();
  }
  bsum2[t] = make_uint2(shl[t] - v.x, shh[t] - v.y);  // exclusive
}

__global__ __launch_bounds__(256) void dscan_write(const unsigned* __restrict__ offsets,
                                                   const uint2* __restrict__ bsum2,
                                                   unsigned* __restrict__ Llist,
                                                   unsigned* __restrict__ Hlist,
                                                   unsigned* __restrict__ nlh) {
  __shared__ unsigned shl[256], shh[256];
  const int t = threadIdx.x;
  const int v0 = (blockIdx.x * 256 + t) * 4;
  const uint4 o = *(const uint4*)(offsets + v0);
  const unsigned o4 = offsets[v0 + 4];
  unsigned cnt[4] = {o.y - o.x, o.z - o.y, o.w - o.z, o4 - o.w};
  unsigned lf[4], hf[4], lt = 0, ht = 0;
#pragma unroll
  for (int k = 0; k < 4; ++k) {
    lf[k] = (cnt[k] >= 1 && cnt[k] <= kTh) ? 1u : 0u;
    hf[k] = (cnt[k] > kTh) ? 1u : 0u;
    lt += lf[k];
    ht += hf[k];
  }
  shl[t] = lt;
  shh[t] = ht;
  __syncthreads();
  for (int d = 1; d < 256; d <<= 1) {
    const unsigned xl = (t >= d) ? shl[t - d] : 0u;
    const unsigned xh = (t >= d) ? shh[t - d] : 0u;
    __syncthreads();
    shl[t] += xl;
    shh[t] += xh;
    __syncthreads();
  }
  unsigned lbase = bsum2[blockIdx.x].x + shl[t] - lt;
  unsigned hbase = bsum2[blockIdx.x].y + shh[t] - ht;
#pragma unroll
  for (int k = 0; k < 4; ++k) {
    if (lf[k]) Llist[lbase++] = (unsigned)(v0 + k);
    if (hf[k]) Hlist[hbase++] = (unsigned)(v0 + k);
  }
  if (blockIdx.x == 255 && t == 255) {
    nlh[0] = lbase;
    nlh[1] = hbase;
  }
}

// --- Kernel F: transpose feat (B,C,N) -> SORTED rows feat_t[off[h]+lr][c] ----
__global__ __launch_bounds__(256) void tr_kernel(const float* __restrict__ feat,
                                                 const unsigned short* __restrict__ hashes,
                                                 const unsigned* __restrict__ lr,
                                                 const unsigned* __restrict__ offsets,
                                                 float* __restrict__ feat_t, int b0) {
  const int b2 = blockIdx.y;
  const int b = b0 + b2;
  const int n0 = blockIdx.x * 32;
  __shared__ float tile[64][33];
  __shared__ unsigned shr[32];
  if (threadIdx.x < 32) {
    const int n = n0 + threadIdx.x;
    const unsigned hh = hashes[(size_t)b * kN + n];
    const unsigned l = lr[(size_t)b * kN + n];
    shr[threadIdx.x] = offsets[(size_t)b * kR3 + hh] + l - (unsigned)b0 * (unsigned)kN;
  }
  const float* fb = feat + (size_t)b * kC * kN;
#pragma unroll
  for (int j = 0; j < 2; ++j) {
    const int idx = j * 256 + threadIdx.x;  // 0..511
    const int c = idx >> 3;
    const int q = idx & 7;
    const float4 v = *(const float4*)(fb + (size_t)c * kN + n0 + q * 4);
    tile[c][q * 4 + 0] = v.x;
    tile[c][q * 4 + 1] = v.y;
    tile[c][q * 4 + 2] = v.z;
    tile[c][q * 4 + 3] = v.w;
  }
  __syncthreads();
#pragma unroll
  for (int j = 0; j < 2; ++j) {
    const int idx = j * 256 + threadIdx.x;  // 0..511
    const int n = idx >> 4;
    const int cq = idx & 15;
    float4 w;
    w.x = tile[cq * 4 + 0][n];
    w.y = tile[cq * 4 + 1][n];
    w.z = tile[cq * 4 + 2][n];
    w.w = tile[cq * 4 + 3][n];
    const size_t row = (size_t)shr[n];
    *(float4*)(feat_t + row * kC + cq * 4) = w;
  }
}

// --- Kernel G1: light voxels (1..kTh rows): wave handles 4 list entries ------
__global__ __launch_bounds__(256) void gather_light(const float* __restrict__ feat_t,
                                                    const unsigned* __restrict__ offsets,
                                                    const unsigned* __restrict__ Llist,
                                                    const unsigned* __restrict__ nlh,
                                                    float* __restrict__ out, int b0,
                                                    int chunkB) {
  const unsigned nl = nlh[0];
  const int wid = blockIdx.x * 4 + (threadIdx.x >> 6);
  const int lane = threadIdx.x & 63;
  const int p = lane >> 4;   // list slot 0..3
  const int cq = lane & 15;  // channel quad
  const unsigned i0 = (unsigned)wid * 4;
  if (i0 >= nl) return;
  const unsigned ip = i0 + (unsigned)p;
  bool act = ip < nl;
  const unsigned v = Llist[act ? ip : i0];
  const unsigned vlo = (unsigned)b0 * (unsigned)kR3;
  const unsigned vhi = (unsigned)(b0 + chunkB) * (unsigned)kR3;
  act = act && (v >= vlo) && (v < vhi);
  const unsigned s = offsets[v];
  unsigned e = offsets[v + 1];
  if (!act) e = s;
  const unsigned rb = (unsigned)b0 * (unsigned)kN;
  const float* ft = feat_t + cq * 4;
  float4 acc = make_float4(0.f, 0.f, 0.f, 0.f);
  unsigned r = s;
  for (; r + 2 <= e; r += 2) {
    const float4 f0 = *(const float4*)(ft + (size_t)(r - rb) * kC);
    const float4 f1 = *(const float4*)(ft + (size_t)(r + 1 - rb) * kC);
    f4add(acc, f0);
    f4add(acc, f1);
  }
  if (r < e) {
    const float4 f0 = *(const float4*)(ft + (size_t)(r - rb) * kC);
    f4add(acc, f0);
  }
  if (act) {
    const float k = (float)(e - s);
    const int b = (int)(v >> 15);
    const int h = (int)(v & (kR3 - 1));
    float* ob = out + ((size_t)b * kC + cq * 4) * kR3 + h;
    ob[0] = acc.x / k;
    ob[(size_t)kR3] = acc.y / k;
    ob[(size_t)2 * kR3] = acc.z / k;
    ob[(size_t)3 * kR3] = acc.w / k;
  }
}

// --- Kernel G2: heavy voxels (>kTh rows): one 256-thread block per voxel -----
__global__ __launch_bounds__(256) void gather_heavy(const float* __restrict__ feat_t,
                                                    const unsigned* __restrict__ offsets,
                                                    const unsigned* __restrict__ Hlist,
                                                    const unsigned* __restrict__ nlh,
                                                    float* __restrict__ out, int b0,
                                                    int chunkB) {
  const unsigned nh = nlh[1];
  if (blockIdx.x >= nh) return;
  const unsigned v = Hlist[blockIdx.x];
  const unsigned vlo = (unsigned)b0 * (unsigned)kR3;
  const unsigned vhi = (unsigned)(b0 + chunkB) * (unsigned)kR3;
  if (v < vlo || v >= vhi) return;
  const unsigned s = offsets[v];
  const unsigned e = offsets[v + 1];
  const int slot = threadIdx.x >> 4;  // row slot 0..15
  const int cq = threadIdx.x & 15;    // channel quad
  const unsigned rb = (unsigned)b0 * (unsigned)kN;
  float4 acc = make_float4(0.f, 0.f, 0.f, 0.f);
  for (unsigned r = s + (unsigned)slot; r < e; r += 16) {
    const float4 f = *(const float4*)(feat_t + (size_t)(r - rb) * kC + cq * 4);
    f4add(acc, f);
  }
  __shared__ float sh[16][64];
  sh[slot][cq * 4 + 0] = acc.x;
  sh[slot][cq * 4 + 1] = acc.y;
  sh[slot][cq * 4 + 2] = acc.z;
  sh[slot][cq * 4 + 3] = acc.w;
  __syncthreads();
  if (threadIdx.x < 64) {
    const int c = threadIdx.x;
    float t = 0.f;
#pragma unroll
    for (int k = 0; k < 16; ++k) t += sh[k][c];
    const int b = (int)(v >> 15);
    const int h = (int)(v & (kR3 - 1));
    out[((size_t)b * kC + c) * kR3 + h] = t / (float)(e - s);
  }
}

// --------------- Fallback: direct atomics into out (b,c,h) -------------------
__global__ __launch_bounds__(256) void scatter_direct(
    const float* __restrict__ feat, const float* __restrict__ coords,
    const double* __restrict__ dsum, const unsigned* __restrict__ maxbits,
    float* __restrict__ gridsum, float* __restrict__ out_nc,
    unsigned* __restrict__ counts) {
  const int b = blockIdx.y;
  const int n0 = (blockIdx.x * 256 + threadIdx.x) * 4;
  if (n0 >= kN) return;
  int h[4];
  point_geom(coords, dsum, maxbits, out_nc, b, n0, h);
  unsigned* cnt = counts + (size_t)b * kR3;
  atomicAdd(&cnt[h[0]], 1u);
  atomicAdd(&cnt[h[1]], 1u);
  atomicAdd(&cnt[h[2]], 1u);
  atomicAdd(&cnt[h[3]], 1u);
  const float* fb = feat + (size_t)b * kC * kN + n0;
  float* gb = gridsum + (size_t)b * kC * kR3;
#pragma unroll 8
  for (int c = 0; c < kC; ++c) {
    const float4 f = *(const float4*)(fb + (size_t)c * kN);
    float* g = gb + (size_t)c * kR3;
    unsafeAtomicAdd(g + h[0], f.x);
    unsafeAtomicAdd(g + h[1], f.y);
    unsafeAtomicAdd(g + h[2], f.z);
    unsafeAtomicAdd(g + h[3], f.w);
  }
}

__global__ __launch_bounds__(256) void divide_inplace(float* __restrict__ grid,
                                                      const unsigned* __restrict__ counts) {
  const size_t e = ((size_t)blockIdx.x * blockDim.x + threadIdx.x) * 4;
  if (e >= kGridElems) return;
  const int h = (int)(e & (size_t)(kR3 - 1));
  const int b = (int)(e >> 21);
  const uint4 cnt = *(const uint4*)(counts + (size_t)b * kR3 + h);
  float4 g = *(float4*)(grid + e);
  g.x = g.x / (float)(cnt.x > 1u ? cnt.x : 1u);
  g.y = g.y / (float)(cnt.y > 1u ? cnt.y : 1u);
  g.z = g.z / (float)(cnt.z > 1u ? cnt.z : 1u);
  g.w = g.w / (float)(cnt.w > 1u ? cnt.w : 1u);
  *(float4*)(grid + e) = g;
}

extern "C" void kernel_launch(void* const* d_in, const int* in_sizes, int n_in,
                              void* d_out, int out_size, void* d_ws, size_t ws_size,
                              hipStream_t stream) {
  const float* feat = (const float*)d_in[0];    // (8, 64, 100000)
  const float* coords = (const float*)d_in[1];  // (8, 3, 100000)
  float* out = (float*)d_out;
  float* out_nc = out + kGridElems;  // (8, 3, 100000)

  char* ws = (char*)d_ws;
  double* dsum = (double*)(ws + kDsumOff);
  unsigned* maxbits = (unsigned*)(ws + kMaxOff);
  unsigned* nlh = (unsigned*)(ws + kNlhOff);
  unsigned* bsum = (unsigned*)(ws + kBsumOff);
  uint2* bsum2 = (uint2*)(ws + kBsum2Off);
  unsigned* counts = (unsigned*)(ws + kCountsOff);
  unsigned* Llist = counts;  // counts region reused after scan_write
  unsigned* offsets = (unsigned*)(ws + kOffsetsOff);
  unsigned* Hlist = (unsigned*)(ws + kHlistOff);
  unsigned short* hashes = (unsigned short*)(ws + kHashOff);
  unsigned* lr = (unsigned*)(ws + kLrOff);
  float* feat_t = (float*)(ws + kFeatTOff);

  const dim3 blk(256);
  const int pblk = (kN / 4 + 255) / 256;  // 98 point-blocks per batch

  // zero header (incl. nlh) + counts (rest is fully rewritten each call)
  hipMemsetAsync(ws, 0, kCountsOff + (size_t)kNV * sizeof(unsigned), stream);

  mean_kernel<<<dim3(32, kB), blk, 0, stream>>>(coords, dsum);
  maxnorm_kernel<<<dim3(32, kB), blk, 0, stream>>>(coords, dsum, maxbits);

  int chunkB = 0;
  for (int c = kB; c >= 1; c >>= 1) {
    if (ws_size >= wsNeed(c)) { chunkB = c; break; }
  }

  if (chunkB) {
    hash_nc_kernel<<<dim3(pblk, kB), blk, 0, stream>>>(coords, dsum, maxbits, out_nc,
                                                       hashes, lr, counts);
    scan_reduce<<<dim3(256), blk, 0, stream>>>(counts, bsum);
    scan_bsum<<<dim3(1), blk, 0, stream>>>(bsum);
    scan_write<<<dim3(256), blk, 0, stream>>>(counts, bsum, offsets);
    dscan_reduce<<<dim3(256), blk, 0, stream>>>(offsets, bsum2);
    dscan_bsum<<<dim3(1), blk, 0, stream>>>(bsum2);
    dscan_write<<<dim3(256), blk, 0, stream>>>(offsets, bsum2, Llist, Hlist, nlh);

    // zeros for empty voxels come from this fill; gathers write occupied only
    hipMemsetAsync(out, 0, kGridElems * sizeof(float), stream);

    for (int b0 = 0; b0 < kB; b0 += chunkB) {
      tr_kernel<<<dim3(kN / 32, chunkB), blk, 0, stream>>>(feat, hashes, lr, offsets,
                                                           feat_t, b0);
      gather_light<<<dim3(kNV / 16), blk, 0, stream>>>(feat_t, offsets, Llist, nlh, out,
                                                       b0, chunkB);
      gather_heavy<<<dim3(kMaxHeavy), blk, 0, stream>>>(feat_t, offsets, Hlist, nlh, out,
                                                        b0, chunkB);
    }
  } else {
    // fallback: direct atomics into final layout
    hipMemsetAsync(out, 0, kGridElems * sizeof(float), stream);
    scatter_direct<<<dim3(pblk, kB), blk, 0, stream>>>(feat, coords, dsum, maxbits, out,
                                                       out_nc, counts);
    const size_t vec4 = kGridElems / 4;
    divide_inplace<<<dim3((unsigned)((vec4 + 255) / 256)), blk, 0, stream>>>(out, counts);
  }
}

// Round 11
// 244.663 us; speedup vs baseline: 1.4473x; 1.0289x over previous
//
#include <hip/hip_runtime.h>

namespace {
constexpr int kB = 8;
constexpr int kC = 64;
constexpr int kN = 100000;
constexpr int kR = 32;
constexpr int kR3 = kR * kR * kR;                     // 32768
constexpr size_t kGridElems = (size_t)kB * kC * kR3;  // 16,777,216
constexpr int kNV = kB * kR3;                         // 262144 voxel bins
constexpr int kNQ = kNV / 4;                          // 65536
constexpr unsigned kTh = 32;                          // light/heavy row threshold
constexpr int kMaxHeavy = kB * kN / (int)(kTh + 1) + 2;  // <= 24244

// ws layout (bytes)
constexpr size_t kDsumOff = 0;                                 // 192 B
constexpr size_t kMaxOff = 192;                                // 32 B
constexpr size_t kNlhOff = 240;                                // 2 uints
constexpr size_t kBsum3Off = 1024;                             // uint4[256] = 4 KB
constexpr size_t kCountsOff = 8192;                            // 1 MB
constexpr size_t kOffsetsOff = kCountsOff + (size_t)kNV * 4;   // (kNV+64) uints
constexpr size_t kLlistOff = kOffsetsOff + (size_t)(kNV + 64) * 4;  // u32 x kNV
constexpr size_t kHlistOff = kLlistOff + (size_t)kNV * 4;      // u32 x kNQ
constexpr size_t kHashOff = kHlistOff + (size_t)kNQ * 4;       // u16 x 800000
constexpr size_t kLrOff = kHashOff + (size_t)kB * kN * 2;      // u32 x 800000
constexpr size_t kFeatTOff = kLrOff + (size_t)kB * kN * 4;
inline size_t wsNeed(int chunkB) { return kFeatTOff + (size_t)chunkB * kN * kC * 4; }
}  // namespace

__device__ __forceinline__ void f4add(float4& a, const float4& f) {
  a.x += f.x; a.y += f.y; a.z += f.z; a.w += f.w;
}

// -------------------- zero-fill for the grid region (fast) -------------------
__global__ __launch_bounds__(256) void zfill_kernel(float4* __restrict__ p) {
  p[(size_t)blockIdx.x * 256 + threadIdx.x] = make_float4(0.f, 0.f, 0.f, 0.f);
}

// ---------------- Kernel A: per-batch coordinate sums (double) ----------------
__global__ __launch_bounds__(256) void mean_kernel(const float* __restrict__ coords,
                                                   double* __restrict__ dsum) {
  const int b = blockIdx.y;
  const int tid = blockIdx.x * blockDim.x + threadIdx.x;
  const int stride = gridDim.x * blockDim.x;
  const float* cb = coords + (size_t)b * 3 * kN;
  double s0 = 0.0, s1 = 0.0, s2 = 0.0;
  for (int n = tid; n < kN; n += stride) {
    s0 += (double)cb[n];
    s1 += (double)cb[kN + n];
    s2 += (double)cb[2 * kN + n];
  }
  __shared__ double sh[3][256];
  sh[0][threadIdx.x] = s0;
  sh[1][threadIdx.x] = s1;
  sh[2][threadIdx.x] = s2;
  __syncthreads();
  for (int off = 128; off > 0; off >>= 1) {
    if (threadIdx.x < (unsigned)off) {
      sh[0][threadIdx.x] += sh[0][threadIdx.x + off];
      sh[1][threadIdx.x] += sh[1][threadIdx.x + off];
      sh[2][threadIdx.x] += sh[2][threadIdx.x + off];
    }
    __syncthreads();
  }
  if (threadIdx.x == 0) {
    atomicAdd(&dsum[b * 3 + 0], sh[0][0]);
    atomicAdd(&dsum[b * 3 + 1], sh[1][0]);
    atomicAdd(&dsum[b * 3 + 2], sh[2][0]);
  }
}

// ------------- Kernel B: per-batch max of squared norm (f32, no fma) ----------
__global__ __launch_bounds__(256) void maxnorm_kernel(const float* __restrict__ coords,
                                                      const double* __restrict__ dsum,
                                                      unsigned* __restrict__ maxbits) {
#pragma clang fp contract(off)
  const int b = blockIdx.y;
  const int tid = blockIdx.x * blockDim.x + threadIdx.x;
  const int stride = gridDim.x * blockDim.x;
  const float* cb = coords + (size_t)b * 3 * kN;
  const float m0 = (float)(dsum[b * 3 + 0] / (double)kN);
  const float m1 = (float)(dsum[b * 3 + 1] / (double)kN);
  const float m2 = (float)(dsum[b * 3 + 2] / (double)kN);
  float mx = 0.0f;
  for (int n = tid; n < kN; n += stride) {
    float x = cb[n] - m0;
    float y = cb[kN + n] - m1;
    float z = cb[2 * kN + n] - m2;
    float sx = x * x;
    float sy = y * y;
    float sz = z * z;
    float s = (sx + sy) + sz;  // match numpy's non-fused order
    mx = fmaxf(mx, s);
  }
  __shared__ float sh[256];
  sh[threadIdx.x] = mx;
  __syncthreads();
  for (int off = 128; off > 0; off >>= 1) {
    if (threadIdx.x < (unsigned)off)
      sh[threadIdx.x] = fmaxf(sh[threadIdx.x], sh[threadIdx.x + off]);
    __syncthreads();
  }
  if (threadIdx.x == 0) atomicMax(&maxbits[b], __float_as_uint(sh[0]));
}

// ---------- common per-point geometry: returns h[4], writes norm_coords ------
__device__ __forceinline__ void point_geom(const float* __restrict__ coords,
                                           const double* __restrict__ dsum,
                                           const unsigned* __restrict__ maxbits,
                                           float* __restrict__ out_nc, int b, int n0,
                                           int h[4]) {
#pragma clang fp contract(off)
  const float m0 = (float)(dsum[b * 3 + 0] / (double)kN);
  const float m1 = (float)(dsum[b * 3 + 1] / (double)kN);
  const float m2 = (float)(dsum[b * 3 + 2] / (double)kN);
  const float scale = 2.0f * sqrtf(__uint_as_float(maxbits[b]));

  const float* cb = coords + (size_t)b * 3 * kN;
  const float4 cx = *(const float4*)(cb + n0);
  const float4 cy = *(const float4*)(cb + kN + n0);
  const float4 cz = *(const float4*)(cb + 2 * kN + n0);

  float xa[4] = {cx.x, cx.y, cx.z, cx.w};
  float ya[4] = {cy.x, cy.y, cy.z, cy.w};
  float za[4] = {cz.x, cz.y, cz.z, cz.w};
  float vx[4], vy[4], vz[4];
#pragma unroll
  for (int k = 0; k < 4; ++k) {
    float tx = (xa[k] - m0) / scale + 0.5f;
    float ty = (ya[k] - m1) / scale + 0.5f;
    float tz = (za[k] - m2) / scale + 0.5f;
    vx[k] = fminf(fmaxf(tx * 32.0f, 0.0f), 31.0f);
    vy[k] = fminf(fmaxf(ty * 32.0f, 0.0f), 31.0f);
    vz[k] = fminf(fmaxf(tz * 32.0f, 0.0f), 31.0f);
    int ix = (int)rintf(vx[k]);
    int iy = (int)rintf(vy[k]);
    int iz = (int)rintf(vz[k]);
    h[k] = ix * (kR * kR) + iy * kR + iz;
  }
  float* nb = out_nc + (size_t)b * 3 * kN;
  *(float4*)(nb + n0) = make_float4(vx[0], vx[1], vx[2], vx[3]);
  *(float4*)(nb + kN + n0) = make_float4(vy[0], vy[1], vy[2], vy[3]);
  *(float4*)(nb + 2 * kN + n0) = make_float4(vz[0], vz[1], vz[2], vz[3]);
}

// - Kernel C: hash + nc + count histogram + local rank (800k uint atomics) ----
__global__ __launch_bounds__(256) void hash_nc_kernel(
    const float* __restrict__ coords, const double* __restrict__ dsum,
    const unsigned* __restrict__ maxbits, float* __restrict__ out_nc,
    unsigned short* __restrict__ hashes, unsigned* __restrict__ lr,
    unsigned* __restrict__ counts) {
  const int b = blockIdx.y;
  const int n0 = (blockIdx.x * 256 + threadIdx.x) * 4;
  if (n0 >= kN) return;
  int h[4];
  point_geom(coords, dsum, maxbits, out_nc, b, n0, h);
  ushort4 h4;
  h4.x = (unsigned short)h[0];
  h4.y = (unsigned short)h[1];
  h4.z = (unsigned short)h[2];
  h4.w = (unsigned short)h[3];
  *(ushort4*)(hashes + (size_t)b * kN + n0) = h4;
  unsigned* cnt = counts + (size_t)b * kR3;
  uint4 l;
  l.x = atomicAdd(&cnt[h[0]], 1u);
  l.y = atomicAdd(&cnt[h[1]], 1u);
  l.z = atomicAdd(&cnt[h[2]], 1u);
  l.w = atomicAdd(&cnt[h[3]], 1u);
  *(uint4*)(lr + (size_t)b * kN + n0) = l;
}

// ------------ fused scan (3 kernels): offsets + light/heavy lists ------------
__global__ __launch_bounds__(256) void scan_reduce(const unsigned* __restrict__ counts,
                                                   uint4* __restrict__ bsum3) {
  __shared__ unsigned sht[256], shl[256], shh[256];
  const int t = threadIdx.x;
  const uint4 c = ((const uint4*)counts)[blockIdx.x * 256 + t];
  const unsigned cnt[4] = {c.x, c.y, c.z, c.w};
  unsigned tot = 0, lt = 0, ht = 0;
#pragma unroll
  for (int k = 0; k < 4; ++k) {
    tot += cnt[k];
    lt += (cnt[k] >= 1u && cnt[k] <= kTh) ? 1u : 0u;
    ht += (cnt[k] > kTh) ? 1u : 0u;
  }
  sht[t] = tot;
  shl[t] = lt;
  shh[t] = ht;
  __syncthreads();
  for (int off = 128; off > 0; off >>= 1) {
    if (t < off) {
      sht[t] += sht[t + off];
      shl[t] += shl[t + off];
      shh[t] += shh[t + off];
    }
    __syncthreads();
  }
  if (t == 0) bsum3[blockIdx.x] = make_uint4(sht[0], shl[0], shh[0], 0u);
}

__global__ __launch_bounds__(256) void scan_bsum(uint4* __restrict__ bsum3) {
  __shared__ unsigned sht[256], shl[256], shh[256];
  const int t = threadIdx.x;
  const uint4 v = bsum3[t];
  sht[t] = v.x;
  shl[t] = v.y;
  shh[t] = v.z;
  __syncthreads();
  for (int d = 1; d < 256; d <<= 1) {
    const unsigned xt = (t >= d) ? sht[t - d] : 0u;
    const unsigned xl = (t >= d) ? shl[t - d] : 0u;
    const unsigned xh = (t >= d) ? shh[t - d] : 0u;
    __syncthreads();
    sht[t] += xt;
    shl[t] += xl;
    shh[t] += xh;
    __syncthreads();
  }
  bsum3[t] = make_uint4(sht[t] - v.x, shl[t] - v.y, shh[t] - v.z, 0u);  // exclusive
}

__global__ __launch_bounds__(256) void scan_write(const unsigned* __restrict__ counts,
                                                  const uint4* __restrict__ bsum3,
                                                  unsigned* __restrict__ offsets,
                                                  unsigned* __restrict__ Llist,
                                                  unsigned* __restrict__ Hlist,
                                                  unsigned* __restrict__ nlh) {
  __shared__ unsigned sht[256], shl[256], shh[256];
  const int t = threadIdx.x;
  const int gi = blockIdx.x * 256 + t;
  const int v0 = gi * 4;
  const uint4 c = ((const uint4*)counts)[gi];
  const unsigned cnt[4] = {c.x, c.y, c.z, c.w};
  unsigned lf[4], hf[4], tot = 0, lt = 0, ht = 0;
#pragma unroll
  for (int k = 0; k < 4; ++k) {
    lf[k] = (cnt[k] >= 1u && cnt[k] <= kTh) ? 1u : 0u;
    hf[k] = (cnt[k] > kTh) ? 1u : 0u;
    tot += cnt[k];
    lt += lf[k];
    ht += hf[k];
  }
  sht[t] = tot;
  shl[t] = lt;
  shh[t] = ht;
  __syncthreads();
  for (int d = 1; d < 256; d <<= 1) {
    const unsigned xt = (t >= d) ? sht[t - d] : 0u;
    const unsigned xl = (t >= d) ? shl[t - d] : 0u;
    const unsigned xh = (t >= d) ? shh[t - d] : 0u;
    __syncthreads();
    sht[t] += xt;
    shl[t] += xl;
    shh[t] += xh;
    __syncthreads();
  }
  const uint4 bs = bsum3[blockIdx.x];
  const unsigned base = bs.x + sht[t] - tot;
  uint4 o;
  o.x = base;
  o.y = o.x + cnt[0];
  o.z = o.y + cnt[1];
  o.w = o.z + cnt[2];
  ((uint4*)offsets)[gi] = o;
  if (gi == kNV / 4 - 1) offsets[kNV] = o.w + cnt[3];  // total = B*N
  unsigned lbase = bs.y + shl[t] - lt;
  unsigned hbase = bs.z + shh[t] - ht;
#pragma unroll
  for (int k = 0; k < 4; ++k) {
    if (lf[k]) Llist[lbase++] = (unsigned)(v0 + k);
    if (hf[k]) Hlist[hbase++] = (unsigned)(v0 + k);
  }
  if (blockIdx.x == 255 && t == 255) {
    nlh[0] = lbase;
    nlh[1] = hbase;
  }
}

// --- Kernel F: transpose feat (B,C,N) -> SORTED rows feat_t[off[h]+lr][c] ----
__global__ __launch_bounds__(256) void tr_kernel(const float* __restrict__ feat,
                                                 const unsigned short* __restrict__ hashes,
                                                 const unsigned* __restrict__ lr,
                                                 const unsigned* __restrict__ offsets,
                                                 float* __restrict__ feat_t, int b0) {
  const int b2 = blockIdx.y;
  const int b = b0 + b2;
  const int n0 = blockIdx.x * 32;
  __shared__ float tile[64][33];
  __shared__ unsigned shr[32];
  if (threadIdx.x < 32) {
    const int n = n0 + threadIdx.x;
    const unsigned hh = hashes[(size_t)b * kN + n];
    const unsigned l = lr[(size_t)b * kN + n];
    shr[threadIdx.x] = offsets[(size_t)b * kR3 + hh] + l - (unsigned)b0 * (unsigned)kN;
  }
  const float* fb = feat + (size_t)b * kC * kN;
#pragma unroll
  for (int j = 0; j < 2; ++j) {
    const int idx = j * 256 + threadIdx.x;  // 0..511
    const int c = idx >> 3;
    const int q = idx & 7;
    const float4 v = *(const float4*)(fb + (size_t)c * kN + n0 + q * 4);
    tile[c][q * 4 + 0] = v.x;
    tile[c][q * 4 + 1] = v.y;
    tile[c][q * 4 + 2] = v.z;
    tile[c][q * 4 + 3] = v.w;
  }
  __syncthreads();
#pragma unroll
  for (int j = 0; j < 2; ++j) {
    const int idx = j * 256 + threadIdx.x;  // 0..511
    const int n = idx >> 4;
    const int cq = idx & 15;
    float4 w;
    w.x = tile[cq * 4 + 0][n];
    w.y = tile[cq * 4 + 1][n];
    w.z = tile[cq * 4 + 2][n];
    w.w = tile[cq * 4 + 3][n];
    const size_t row = (size_t)shr[n];
    *(float4*)(feat_t + row * kC + cq * 4) = w;
  }
}

// --- Kernel G1: light voxels (1..kTh rows): wave handles 4 list entries ------
__global__ __launch_bounds__(256) void gather_light(const float* __restrict__ feat_t,
                                                    const unsigned* __restrict__ offsets,
                                                    const unsigned* __restrict__ Llist,
                                                    const unsigned* __restrict__ nlh,
                                                    float* __restrict__ out, int b0,
                                                    int chunkB) {
  const unsigned nl = nlh[0];
  const int wid = blockIdx.x * 4 + (threadIdx.x >> 6);
  const int lane = threadIdx.x & 63;
  const int p = lane >> 4;   // list slot 0..3
  const int cq = lane & 15;  // channel quad
  const unsigned i0 = (unsigned)wid * 4;
  if (i0 >= nl) return;
  const unsigned ip = i0 + (unsigned)p;
  bool act = ip < nl;
  const unsigned v = Llist[act ? ip : i0];
  const unsigned vlo = (unsigned)b0 * (unsigned)kR3;
  const unsigned vhi = (unsigned)(b0 + chunkB) * (unsigned)kR3;
  act = act && (v >= vlo) && (v < vhi);
  const unsigned s = offsets[v];
  unsigned e = offsets[v + 1];
  if (!act) e = s;
  const unsigned rb = (unsigned)b0 * (unsigned)kN;
  const float* ft = feat_t + cq * 4;
  float4 acc = make_float4(0.f, 0.f, 0.f, 0.f);
  unsigned r = s;
  for (; r + 2 <= e; r += 2) {
    const float4 f0 = *(const float4*)(ft + (size_t)(r - rb) * kC);
    const float4 f1 = *(const float4*)(ft + (size_t)(r + 1 - rb) * kC);
    f4add(acc, f0);
    f4add(acc, f1);
  }
  if (r < e) {
    const float4 f0 = *(const float4*)(ft + (size_t)(r - rb) * kC);
    f4add(acc, f0);
  }
  if (act) {
    const float k = (float)(e - s);
    const int b = (int)(v >> 15);
    const int h = (int)(v & (kR3 - 1));
    float* ob = out + ((size_t)b * kC + cq * 4) * kR3 + h;
    ob[0] = acc.x / k;
    ob[(size_t)kR3] = acc.y / k;
    ob[(size_t)2 * kR3] = acc.z / k;
    ob[(size_t)3 * kR3] = acc.w / k;
  }
}

// --- Kernel G2: heavy voxels (>kTh rows): one 256-thread block per voxel -----
__global__ __launch_bounds__(256) void gather_heavy(const float* __restrict__ feat_t,
                                                    const unsigned* __restrict__ offsets,
                                                    const unsigned* __restrict__ Hlist,
                                                    const unsigned* __restrict__ nlh,
                                                    float* __restrict__ out, int b0,
                                                    int chunkB) {
  const unsigned nh = nlh[1];
  if (blockIdx.x >= nh) return;
  const unsigned v = Hlist[blockIdx.x];
  const unsigned vlo = (unsigned)b0 * (unsigned)kR3;
  const unsigned vhi = (unsigned)(b0 + chunkB) * (unsigned)kR3;
  if (v < vlo || v >= vhi) return;
  const unsigned s = offsets[v];
  const unsigned e = offsets[v + 1];
  const int slot = threadIdx.x >> 4;  // row slot 0..15
  const int cq = threadIdx.x & 15;    // channel quad
  const unsigned rb = (unsigned)b0 * (unsigned)kN;
  float4 acc = make_float4(0.f, 0.f, 0.f, 0.f);
  for (unsigned r = s + (unsigned)slot; r < e; r += 16) {
    const float4 f = *(const float4*)(feat_t + (size_t)(r - rb) * kC + cq * 4);
    f4add(acc, f);
  }
  __shared__ float sh[16][64];
  sh[slot][cq * 4 + 0] = acc.x;
  sh[slot][cq * 4 + 1] = acc.y;
  sh[slot][cq * 4 + 2] = acc.z;
  sh[slot][cq * 4 + 3] = acc.w;
  __syncthreads();
  if (threadIdx.x < 64) {
    const int c = threadIdx.x;
    float t = 0.f;
#pragma unroll
    for (int k = 0; k < 16; ++k) t += sh[k][c];
    const int b = (int)(v >> 15);
    const int h = (int)(v & (kR3 - 1));
    out[((size_t)b * kC + c) * kR3 + h] = t / (float)(e - s);
  }
}

// --------------- Fallback: direct atomics into out (b,c,h) -------------------
__global__ __launch_bounds__(256) void scatter_direct(
    const float* __restrict__ feat, const float* __restrict__ coords,
    const double* __restrict__ dsum, const unsigned* __restrict__ maxbits,
    float* __restrict__ gridsum, float* __restrict__ out_nc,
    unsigned* __restrict__ counts) {
  const int b = blockIdx.y;
  const int n0 = (blockIdx.x * 256 + threadIdx.x) * 4;
  if (n0 >= kN) return;
  int h[4];
  point_geom(coords, dsum, maxbits, out_nc, b, n0, h);
  unsigned* cnt = counts + (size_t)b * kR3;
  atomicAdd(&cnt[h[0]], 1u);
  atomicAdd(&cnt[h[1]], 1u);
  atomicAdd(&cnt[h[2]], 1u);
  atomicAdd(&cnt[h[3]], 1u);
  const float* fb = feat + (size_t)b * kC * kN + n0;
  float* gb = gridsum + (size_t)b * kC * kR3;
#pragma unroll 8
  for (int c = 0; c < kC; ++c) {
    const float4 f = *(const float4*)(fb + (size_t)c * kN);
    float* g = gb + (size_t)c * kR3;
    unsafeAtomicAdd(g + h[0], f.x);
    unsafeAtomicAdd(g + h[1], f.y);
    unsafeAtomicAdd(g + h[2], f.z);
    unsafeAtomicAdd(g + h[3], f.w);
  }
}

__global__ __launch_bounds__(256) void divide_inplace(float* __restrict__ grid,
                                                      const unsigned* __restrict__ counts) {
  const size_t e = ((size_t)blockIdx.x * blockDim.x + threadIdx.x) * 4;
  if (e >= kGridElems) return;
  const int h = (int)(e & (size_t)(kR3 - 1));
  const int b = (int)(e >> 21);
  const uint4 cnt = *(const uint4*)(counts + (size_t)b * kR3 + h);
  float4 g = *(float4*)(grid + e);
  g.x = g.x / (float)(cnt.x > 1u ? cnt.x : 1u);
  g.y = g.y / (float)(cnt.y > 1u ? cnt.y : 1u);
  g.z = g.z / (float)(cnt.z > 1u ? cnt.z : 1u);
  g.w = g.w / (float)(cnt.w > 1u ? cnt.w : 1u);
  *(float4*)(grid + e) = g;
}

extern "C" void kernel_launch(void* const* d_in, const int* in_sizes, int n_in,
                              void* d_out, int out_size, void* d_ws, size_t ws_size,
                              hipStream_t stream) {
  const float* feat = (const float*)d_in[0];    // (8, 64, 100000)
  const float* coords = (const float*)d_in[1];  // (8, 3, 100000)
  float* out = (float*)d_out;
  float* out_nc = out + kGridElems;  // (8, 3, 100000)

  char* ws = (char*)d_ws;
  double* dsum = (double*)(ws + kDsumOff);
  unsigned* maxbits = (unsigned*)(ws + kMaxOff);
  unsigned* nlh = (unsigned*)(ws + kNlhOff);
  uint4* bsum3 = (uint4*)(ws + kBsum3Off);
  unsigned* counts = (unsigned*)(ws + kCountsOff);
  unsigned* offsets = (unsigned*)(ws + kOffsetsOff);
  unsigned* Llist = (unsigned*)(ws + kLlistOff);
  unsigned* Hlist = (unsigned*)(ws + kHlistOff);
  unsigned short* hashes = (unsigned short*)(ws + kHashOff);
  unsigned* lr = (unsigned*)(ws + kLrOff);
  float* feat_t = (float*)(ws + kFeatTOff);

  const dim3 blk(256);
  const int pblk = (kN / 4 + 255) / 256;  // 98 point-blocks per batch

  // zero header (incl. nlh) + counts (rest is fully rewritten each call)
  hipMemsetAsync(ws, 0, kCountsOff + (size_t)kNV * sizeof(unsigned), stream);

  mean_kernel<<<dim3(32, kB), blk, 0, stream>>>(coords, dsum);
  maxnorm_kernel<<<dim3(32, kB), blk, 0, stream>>>(coords, dsum, maxbits);

  int chunkB = 0;
  for (int c = kB; c >= 1; c >>= 1) {
    if (ws_size >= wsNeed(c)) { chunkB = c; break; }
  }

  if (chunkB) {
    hash_nc_kernel<<<dim3(pblk, kB), blk, 0, stream>>>(coords, dsum, maxbits, out_nc,
                                                       hashes, lr, counts);
    scan_reduce<<<dim3(256), blk, 0, stream>>>(counts, bsum3);
    scan_bsum<<<dim3(1), blk, 0, stream>>>(bsum3);
    scan_write<<<dim3(256), blk, 0, stream>>>(counts, bsum3, offsets, Llist, Hlist, nlh);

    // zeros for empty voxels via fast custom fill (rocclr fill was ~100 us)
    zfill_kernel<<<dim3((unsigned)(kGridElems / 4 / 256)), blk, 0, stream>>>((float4*)out);

    for (int b0 = 0; b0 < kB; b0 += chunkB) {
      tr_kernel<<<dim3(kN / 32, chunkB), blk, 0, stream>>>(feat, hashes, lr, offsets,
                                                           feat_t, b0);
      gather_light<<<dim3(kNV / 16), blk, 0, stream>>>(feat_t, offsets, Llist, nlh, out,
                                                       b0, chunkB);
      gather_heavy<<<dim3(kMaxHeavy), blk, 0, stream>>>(feat_t, offsets, Hlist, nlh, out,
                                                        b0, chunkB);
    }
  } else {
    // fallback: direct atomics into final layout
    zfill_kernel<<<dim3((unsigned)(kGridElems / 4 / 256)), blk, 0, stream>>>((float4*)out);
    scatter_direct<<<dim3(pblk, kB), blk, 0, stream>>>(feat, coords, dsum, maxbits, out,
                                                       out_nc, counts);
    const size_t vec4 = kGridElems / 4;
    divide_inplace<<<dim3((unsigned)((vec4 + 255) / 256)), blk, 0, stream>>>(out, counts);
  }
}

// Round 12
// 243.973 us; speedup vs baseline: 1.4514x; 1.0028x over previous
//
#include <hip/hip_runtime.h>

namespace {
constexpr int kB = 8;
constexpr int kC = 64;
constexpr int kN = 100000;
constexpr int kR = 32;
constexpr int kR3 = kR * kR * kR;                     // 32768
constexpr size_t kGridElems = (size_t)kB * kC * kR3;  // 16,777,216
constexpr int kNV = kB * kR3;                         // 262144 voxel bins
constexpr int kNQ = kNV / 4;                          // 65536
constexpr unsigned kTh = 32;                          // light/heavy row threshold
constexpr int kMaxHeavy = kB * kN / (int)(kTh + 1) + 2;  // <= 24244

// ws layout (bytes)
constexpr size_t kDsumOff = 0;                                 // 192 B
constexpr size_t kMaxOff = 192;                                // 32 B
constexpr size_t kNlhOff = 240;                                // 2 uints
constexpr size_t kBsum3Off = 1024;                             // uint4[256] = 4 KB
constexpr size_t kCountsOff = 8192;                            // 1 MB
constexpr size_t kOffsetsOff = kCountsOff + (size_t)kNV * 4;   // (kNV+64) uints
constexpr size_t kLlistOff = kOffsetsOff + (size_t)(kNV + 64) * 4;  // u32 x kNV
constexpr size_t kHlistOff = kLlistOff + (size_t)kNV * 4;      // u32 x kNQ
constexpr size_t kHashOff = kHlistOff + (size_t)kNQ * 4;       // u16 x 800000
constexpr size_t kLrOff = kHashOff + (size_t)kB * kN * 2;      // u32 x 800000
constexpr size_t kFeatTOff = kLrOff + (size_t)kB * kN * 4;
inline size_t wsNeed(int chunkB) { return kFeatTOff + (size_t)chunkB * kN * kC * 4; }
// ws-header zero size: covers header + counts, float4-exact
constexpr size_t kWsZeroBytes = kCountsOff + (size_t)kNV * 4;  // 1,056,768
constexpr unsigned kWsZeroF4 = (unsigned)(kWsZeroBytes / 16);  // 66,048 = 258*256
}  // namespace

__device__ __forceinline__ void f4add(float4& a, const float4& f) {
  a.x += f.x; a.y += f.y; a.z += f.z; a.w += f.w;
}

// ------------- fast zero-fill (rocclr fillBuffer costs ~115 us in-graph) -----
__global__ __launch_bounds__(256) void zfill_kernel(float4* __restrict__ p) {
  p[(size_t)blockIdx.x * 256 + threadIdx.x] = make_float4(0.f, 0.f, 0.f, 0.f);
}

// ---------------- Kernel A: per-batch coordinate sums (double) ----------------
__global__ __launch_bounds__(256) void mean_kernel(const float* __restrict__ coords,
                                                   double* __restrict__ dsum) {
  const int b = blockIdx.y;
  const int tid = blockIdx.x * blockDim.x + threadIdx.x;
  const int stride = gridDim.x * blockDim.x;
  const float* cb = coords + (size_t)b * 3 * kN;
  double s0 = 0.0, s1 = 0.0, s2 = 0.0;
  for (int n = tid; n < kN; n += stride) {
    s0 += (double)cb[n];
    s1 += (double)cb[kN + n];
    s2 += (double)cb[2 * kN + n];
  }
  __shared__ double sh[3][256];
  sh[0][threadIdx.x] = s0;
  sh[1][threadIdx.x] = s1;
  sh[2][threadIdx.x] = s2;
  __syncthreads();
  for (int off = 128; off > 0; off >>= 1) {
    if (threadIdx.x < (unsigned)off) {
      sh[0][threadIdx.x] += sh[0][threadIdx.x + off];
      sh[1][threadIdx.x] += sh[1][threadIdx.x + off];
      sh[2][threadIdx.x] += sh[2][threadIdx.x + off];
    }
    __syncthreads();
  }
  if (threadIdx.x == 0) {
    atomicAdd(&dsum[b * 3 + 0], sh[0][0]);
    atomicAdd(&dsum[b * 3 + 1], sh[1][0]);
    atomicAdd(&dsum[b * 3 + 2], sh[2][0]);
  }
}

// ------------- Kernel B: per-batch max of squared norm (f32, no fma) ----------
__global__ __launch_bounds__(256) void maxnorm_kernel(const float* __restrict__ coords,
                                                      const double* __restrict__ dsum,
                                                      unsigned* __restrict__ maxbits) {
#pragma clang fp contract(off)
  const int b = blockIdx.y;
  const int tid = blockIdx.x * blockDim.x + threadIdx.x;
  const int stride = gridDim.x * blockDim.x;
  const float* cb = coords + (size_t)b * 3 * kN;
  const float m0 = (float)(dsum[b * 3 + 0] / (double)kN);
  const float m1 = (float)(dsum[b * 3 + 1] / (double)kN);
  const float m2 = (float)(dsum[b * 3 + 2] / (double)kN);
  float mx = 0.0f;
  for (int n = tid; n < kN; n += stride) {
    float x = cb[n] - m0;
    float y = cb[kN + n] - m1;
    float z = cb[2 * kN + n] - m2;
    float sx = x * x;
    float sy = y * y;
    float sz = z * z;
    float s = (sx + sy) + sz;  // match numpy's non-fused order
    mx = fmaxf(mx, s);
  }
  __shared__ float sh[256];
  sh[threadIdx.x] = mx;
  __syncthreads();
  for (int off = 128; off > 0; off >>= 1) {
    if (threadIdx.x < (unsigned)off)
      sh[threadIdx.x] = fmaxf(sh[threadIdx.x], sh[threadIdx.x + off]);
    __syncthreads();
  }
  if (threadIdx.x == 0) atomicMax(&maxbits[b], __float_as_uint(sh[0]));
}

// ---------- common per-point geometry: returns h[4], writes norm_coords ------
__device__ __forceinline__ void point_geom(const float* __restrict__ coords,
                                           const double* __restrict__ dsum,
                                           const unsigned* __restrict__ maxbits,
                                           float* __restrict__ out_nc, int b, int n0,
                                           int h[4]) {
#pragma clang fp contract(off)
  const float m0 = (float)(dsum[b * 3 + 0] / (double)kN);
  const float m1 = (float)(dsum[b * 3 + 1] / (double)kN);
  const float m2 = (float)(dsum[b * 3 + 2] / (double)kN);
  const float scale = 2.0f * sqrtf(__uint_as_float(maxbits[b]));

  const float* cb = coords + (size_t)b * 3 * kN;
  const float4 cx = *(const float4*)(cb + n0);
  const float4 cy = *(const float4*)(cb + kN + n0);
  const float4 cz = *(const float4*)(cb + 2 * kN + n0);

  float xa[4] = {cx.x, cx.y, cx.z, cx.w};
  float ya[4] = {cy.x, cy.y, cy.z, cy.w};
  float za[4] = {cz.x, cz.y, cz.z, cz.w};
  float vx[4], vy[4], vz[4];
#pragma unroll
  for (int k = 0; k < 4; ++k) {
    float tx = (xa[k] - m0) / scale + 0.5f;
    float ty = (ya[k] - m1) / scale + 0.5f;
    float tz = (za[k] - m2) / scale + 0.5f;
    vx[k] = fminf(fmaxf(tx * 32.0f, 0.0f), 31.0f);
    vy[k] = fminf(fmaxf(ty * 32.0f, 0.0f), 31.0f);
    vz[k] = fminf(fmaxf(tz * 32.0f, 0.0f), 31.0f);
    int ix = (int)rintf(vx[k]);
    int iy = (int)rintf(vy[k]);
    int iz = (int)rintf(vz[k]);
    h[k] = ix * (kR * kR) + iy * kR + iz;
  }
  float* nb = out_nc + (size_t)b * 3 * kN;
  *(float4*)(nb + n0) = make_float4(vx[0], vx[1], vx[2], vx[3]);
  *(float4*)(nb + kN + n0) = make_float4(vy[0], vy[1], vy[2], vy[3]);
  *(float4*)(nb + 2 * kN + n0) = make_float4(vz[0], vz[1], vz[2], vz[3]);
}

// - Kernel C: hash + nc + count histogram + local rank (800k uint atomics) ----
__global__ __launch_bounds__(256) void hash_nc_kernel(
    const float* __restrict__ coords, const double* __restrict__ dsum,
    const unsigned* __restrict__ maxbits, float* __restrict__ out_nc,
    unsigned short* __restrict__ hashes, unsigned* __restrict__ lr,
    unsigned* __restrict__ counts) {
  const int b = blockIdx.y;
  const int n0 = (blockIdx.x * 256 + threadIdx.x) * 4;
  if (n0 >= kN) return;
  int h[4];
  point_geom(coords, dsum, maxbits, out_nc, b, n0, h);
  ushort4 h4;
  h4.x = (unsigned short)h[0];
  h4.y = (unsigned short)h[1];
  h4.z = (unsigned short)h[2];
  h4.w = (unsigned short)h[3];
  *(ushort4*)(hashes + (size_t)b * kN + n0) = h4;
  unsigned* cnt = counts + (size_t)b * kR3;
  uint4 l;
  l.x = atomicAdd(&cnt[h[0]], 1u);
  l.y = atomicAdd(&cnt[h[1]], 1u);
  l.z = atomicAdd(&cnt[h[2]], 1u);
  l.w = atomicAdd(&cnt[h[3]], 1u);
  *(uint4*)(lr + (size_t)b * kN + n0) = l;
}

// ------------ fused scan (3 kernels): offsets + light/heavy lists ------------
__global__ __launch_bounds__(256) void scan_reduce(const unsigned* __restrict__ counts,
                                                   uint4* __restrict__ bsum3) {
  __shared__ unsigned sht[256], shl[256], shh[256];
  const int t = threadIdx.x;
  const uint4 c = ((const uint4*)counts)[blockIdx.x * 256 + t];
  const unsigned cnt[4] = {c.x, c.y, c.z, c.w};
  unsigned tot = 0, lt = 0, ht = 0;
#pragma unroll
  for (int k = 0; k < 4; ++k) {
    tot += cnt[k];
    lt += (cnt[k] >= 1u && cnt[k] <= kTh) ? 1u : 0u;
    ht += (cnt[k] > kTh) ? 1u : 0u;
  }
  sht[t] = tot;
  shl[t] = lt;
  shh[t] = ht;
  __syncthreads();
  for (int off = 128; off > 0; off >>= 1) {
    if (t < off) {
      sht[t] += sht[t + off];
      shl[t] += shl[t + off];
      shh[t] += shh[t + off];
    }
    __syncthreads();
  }
  if (t == 0) bsum3[blockIdx.x] = make_uint4(sht[0], shl[0], shh[0], 0u);
}

__global__ __launch_bounds__(256) void scan_bsum(uint4* __restrict__ bsum3) {
  __shared__ unsigned sht[256], shl[256], shh[256];
  const int t = threadIdx.x;
  const uint4 v = bsum3[t];
  sht[t] = v.x;
  shl[t] = v.y;
  shh[t] = v.z;
  __syncthreads();
  for (int d = 1; d < 256; d <<= 1) {
    const unsigned xt = (t >= d) ? sht[t - d] : 0u;
    const unsigned xl = (t >= d) ? shl[t - d] : 0u;
    const unsigned xh = (t >= d) ? shh[t - d] : 0u;
    __syncthreads();
    sht[t] += xt;
    shl[t] += xl;
    shh[t] += xh;
    __syncthreads();
  }
  bsum3[t] = make_uint4(sht[t] - v.x, shl[t] - v.y, shh[t] - v.z, 0u);  // exclusive
}

__global__ __launch_bounds__(256) void scan_write(const unsigned* __restrict__ counts,
                                                  const uint4* __restrict__ bsum3,
                                                  unsigned* __restrict__ offsets,
                                                  unsigned* __restrict__ Llist,
                                                  unsigned* __restrict__ Hlist,
                                                  unsigned* __restrict__ nlh) {
  __shared__ unsigned sht[256], shl[256], shh[256];
  const int t = threadIdx.x;
  const int gi = blockIdx.x * 256 + t;
  const int v0 = gi * 4;
  const uint4 c = ((const uint4*)counts)[gi];
  const unsigned cnt[4] = {c.x, c.y, c.z, c.w};
  unsigned lf[4], hf[4], tot = 0, lt = 0, ht = 0;
#pragma unroll
  for (int k = 0; k < 4; ++k) {
    lf[k] = (cnt[k] >= 1u && cnt[k] <= kTh) ? 1u : 0u;
    hf[k] = (cnt[k] > kTh) ? 1u : 0u;
    tot += cnt[k];
    lt += lf[k];
    ht += hf[k];
  }
  sht[t] = tot;
  shl[t] = lt;
  shh[t] = ht;
  __syncthreads();
  for (int d = 1; d < 256; d <<= 1) {
    const unsigned xt = (t >= d) ? sht[t - d] : 0u;
    const unsigned xl = (t >= d) ? shl[t - d] : 0u;
    const unsigned xh = (t >= d) ? shh[t - d] : 0u;
    __syncthreads();
    sht[t] += xt;
    shl[t] += xl;
    shh[t] += xh;
    __syncthreads();
  }
  const uint4 bs = bsum3[blockIdx.x];
  const unsigned base = bs.x + sht[t] - tot;
  uint4 o;
  o.x = base;
  o.y = o.x + cnt[0];
  o.z = o.y + cnt[1];
  o.w = o.z + cnt[2];
  ((uint4*)offsets)[gi] = o;
  if (gi == kNV / 4 - 1) offsets[kNV] = o.w + cnt[3];  // total = B*N
  unsigned lbase = bs.y + shl[t] - lt;
  unsigned hbase = bs.z + shh[t] - ht;
#pragma unroll
  for (int k = 0; k < 4; ++k) {
    if (lf[k]) Llist[lbase++] = (unsigned)(v0 + k);
    if (hf[k]) Hlist[hbase++] = (unsigned)(v0 + k);
  }
  if (blockIdx.x == 255 && t == 255) {
    nlh[0] = lbase;
    nlh[1] = hbase;
  }
}

// --- Kernel F: transpose feat (B,C,N) -> SORTED rows feat_t[off[h]+lr][c] ----
__global__ __launch_bounds__(256) void tr_kernel(const float* __restrict__ feat,
                                                 const unsigned short* __restrict__ hashes,
                                                 const unsigned* __restrict__ lr,
                                                 const unsigned* __restrict__ offsets,
                                                 float* __restrict__ feat_t, int b0) {
  const int b2 = blockIdx.y;
  const int b = b0 + b2;
  const int n0 = blockIdx.x * 32;
  __shared__ float tile[64][33];
  __shared__ unsigned shr[32];
  if (threadIdx.x < 32) {
    const int n = n0 + threadIdx.x;
    const unsigned hh = hashes[(size_t)b * kN + n];
    const unsigned l = lr[(size_t)b * kN + n];
    shr[threadIdx.x] = offsets[(size_t)b * kR3 + hh] + l - (unsigned)b0 * (unsigned)kN;
  }
  const float* fb = feat + (size_t)b * kC * kN;
#pragma unroll
  for (int j = 0; j < 2; ++j) {
    const int idx = j * 256 + threadIdx.x;  // 0..511
    const int c = idx >> 3;
    const int q = idx & 7;
    const float4 v = *(const float4*)(fb + (size_t)c * kN + n0 + q * 4);
    tile[c][q * 4 + 0] = v.x;
    tile[c][q * 4 + 1] = v.y;
    tile[c][q * 4 + 2] = v.z;
    tile[c][q * 4 + 3] = v.w;
  }
  __syncthreads();
#pragma unroll
  for (int j = 0; j < 2; ++j) {
    const int idx = j * 256 + threadIdx.x;  // 0..511
    const int n = idx >> 4;
    const int cq = idx & 15;
    float4 w;
    w.x = tile[cq * 4 + 0][n];
    w.y = tile[cq * 4 + 1][n];
    w.z = tile[cq * 4 + 2][n];
    w.w = tile[cq * 4 + 3][n];
    const size_t row = (size_t)shr[n];
    *(float4*)(feat_t + row * kC + cq * 4) = w;
  }
}

// --- Kernel G1: light voxels (1..kTh rows): wave handles 4 list entries ------
__global__ __launch_bounds__(256) void gather_light(const float* __restrict__ feat_t,
                                                    const unsigned* __restrict__ offsets,
                                                    const unsigned* __restrict__ Llist,
                                                    const unsigned* __restrict__ nlh,
                                                    float* __restrict__ out, int b0,
                                                    int chunkB) {
  const unsigned nl = nlh[0];
  const int wid = blockIdx.x * 4 + (threadIdx.x >> 6);
  const int lane = threadIdx.x & 63;
  const int p = lane >> 4;   // list slot 0..3
  const int cq = lane & 15;  // channel quad
  const unsigned i0 = (unsigned)wid * 4;
  if (i0 >= nl) return;
  const unsigned ip = i0 + (unsigned)p;
  bool act = ip < nl;
  const unsigned v = Llist[act ? ip : i0];
  const unsigned vlo = (unsigned)b0 * (unsigned)kR3;
  const unsigned vhi = (unsigned)(b0 + chunkB) * (unsigned)kR3;
  act = act && (v >= vlo) && (v < vhi);
  const unsigned s = offsets[v];
  unsigned e = offsets[v + 1];
  if (!act) e = s;
  const unsigned rb = (unsigned)b0 * (unsigned)kN;
  const float* ft = feat_t + cq * 4;
  float4 acc = make_float4(0.f, 0.f, 0.f, 0.f);
  unsigned r = s;
  for (; r + 2 <= e; r += 2) {
    const float4 f0 = *(const float4*)(ft + (size_t)(r - rb) * kC);
    const float4 f1 = *(const float4*)(ft + (size_t)(r + 1 - rb) * kC);
    f4add(acc, f0);
    f4add(acc, f1);
  }
  if (r < e) {
    const float4 f0 = *(const float4*)(ft + (size_t)(r - rb) * kC);
    f4add(acc, f0);
  }
  if (act) {
    const float k = (float)(e - s);
    const int b = (int)(v >> 15);
    const int h = (int)(v & (kR3 - 1));
    float* ob = out + ((size_t)b * kC + cq * 4) * kR3 + h;
    ob[0] = acc.x / k;
    ob[(size_t)kR3] = acc.y / k;
    ob[(size_t)2 * kR3] = acc.z / k;
    ob[(size_t)3 * kR3] = acc.w / k;
  }
}

// --- Kernel G2: heavy voxels (>kTh rows): one 256-thread block per voxel -----
__global__ __launch_bounds__(256) void gather_heavy(const float* __restrict__ feat_t,
                                                    const unsigned* __restrict__ offsets,
                                                    const unsigned* __restrict__ Hlist,
                                                    const unsigned* __restrict__ nlh,
                                                    float* __restrict__ out, int b0,
                                                    int chunkB) {
  const unsigned nh = nlh[1];
  if (blockIdx.x >= nh) return;
  const unsigned v = Hlist[blockIdx.x];
  const unsigned vlo = (unsigned)b0 * (unsigned)kR3;
  const unsigned vhi = (unsigned)(b0 + chunkB) * (unsigned)kR3;
  if (v < vlo || v >= vhi) return;
  const unsigned s = offsets[v];
  const unsigned e = offsets[v + 1];
  const int slot = threadIdx.x >> 4;  // row slot 0..15
  const int cq = threadIdx.x & 15;    // channel quad
  const unsigned rb = (unsigned)b0 * (unsigned)kN;
  float4 acc = make_float4(0.f, 0.f, 0.f, 0.f);
  for (unsigned r = s + (unsigned)slot; r < e; r += 16) {
    const float4 f = *(const float4*)(feat_t + (size_t)(r - rb) * kC + cq * 4);
    f4add(acc, f);
  }
  __shared__ float sh[16][64];
  sh[slot][cq * 4 + 0] = acc.x;
  sh[slot][cq * 4 + 1] = acc.y;
  sh[slot][cq * 4 + 2] = acc.z;
  sh[slot][cq * 4 + 3] = acc.w;
  __syncthreads();
  if (threadIdx.x < 64) {
    const int c = threadIdx.x;
    float t = 0.f;
#pragma unroll
    for (int k = 0; k < 16; ++k) t += sh[k][c];
    const int b = (int)(v >> 15);
    const int h = (int)(v & (kR3 - 1));
    out[((size_t)b * kC + c) * kR3 + h] = t / (float)(e - s);
  }
}

// --------------- Fallback: direct atomics into out (b,c,h) -------------------
__global__ __launch_bounds__(256) void scatter_direct(
    const float* __restrict__ feat, const float* __restrict__ coords,
    const double* __restrict__ dsum, const unsigned* __restrict__ maxbits,
    float* __restrict__ gridsum, float* __restrict__ out_nc,
    unsigned* __restrict__ counts) {
  const int b = blockIdx.y;
  const int n0 = (blockIdx.x * 256 + threadIdx.x) * 4;
  if (n0 >= kN) return;
  int h[4];
  point_geom(coords, dsum, maxbits, out_nc, b, n0, h);
  unsigned* cnt = counts + (size_t)b * kR3;
  atomicAdd(&cnt[h[0]], 1u);
  atomicAdd(&cnt[h[1]], 1u);
  atomicAdd(&cnt[h[2]], 1u);
  atomicAdd(&cnt[h[3]], 1u);
  const float* fb = feat + (size_t)b * kC * kN + n0;
  float* gb = gridsum + (size_t)b * kC * kR3;
#pragma unroll 8
  for (int c = 0; c < kC; ++c) {
    const float4 f = *(const float4*)(fb + (size_t)c * kN);
    float* g = gb + (size_t)c * kR3;
    unsafeAtomicAdd(g + h[0], f.x);
    unsafeAtomicAdd(g + h[1], f.y);
    unsafeAtomicAdd(g + h[2], f.z);
    unsafeAtomicAdd(g + h[3], f.w);
  }
}

__global__ __launch_bounds__(256) void divide_inplace(float* __restrict__ grid,
                                                      const unsigned* __restrict__ counts) {
  const size_t e = ((size_t)blockIdx.x * blockDim.x + threadIdx.x) * 4;
  if (e >= kGridElems) return;
  const int h = (int)(e & (size_t)(kR3 - 1));
  const int b = (int)(e >> 21);
  const uint4 cnt = *(const uint4*)(counts + (size_t)b * kR3 + h);
  float4 g = *(float4*)(grid + e);
  g.x = g.x / (float)(cnt.x > 1u ? cnt.x : 1u);
  g.y = g.y / (float)(cnt.y > 1u ? cnt.y : 1u);
  g.z = g.z / (float)(cnt.z > 1u ? cnt.z : 1u);
  g.w = g.w / (float)(cnt.w > 1u ? cnt.w : 1u);
  *(float4*)(grid + e) = g;
}

extern "C" void kernel_launch(void* const* d_in, const int* in_sizes, int n_in,
                              void* d_out, int out_size, void* d_ws, size_t ws_size,
                              hipStream_t stream) {
  const float* feat = (const float*)d_in[0];    // (8, 64, 100000)
  const float* coords = (const float*)d_in[1];  // (8, 3, 100000)
  float* out = (float*)d_out;
  float* out_nc = out + kGridElems;  // (8, 3, 100000)

  char* ws = (char*)d_ws;
  double* dsum = (double*)(ws + kDsumOff);
  unsigned* maxbits = (unsigned*)(ws + kMaxOff);
  unsigned* nlh = (unsigned*)(ws + kNlhOff);
  uint4* bsum3 = (uint4*)(ws + kBsum3Off);
  unsigned* counts = (unsigned*)(ws + kCountsOff);
  unsigned* offsets = (unsigned*)(ws + kOffsetsOff);
  unsigned* Llist = (unsigned*)(ws + kLlistOff);
  unsigned* Hlist = (unsigned*)(ws + kHlistOff);
  unsigned short* hashes = (unsigned short*)(ws + kHashOff);
  unsigned* lr = (unsigned*)(ws + kLrOff);
  float* feat_t = (float*)(ws + kFeatTOff);

  const dim3 blk(256);
  const int pblk = (kN / 4 + 255) / 256;  // 98 point-blocks per batch

  // zero header (dsum/maxbits/nlh) + counts with the custom fill
  // (in-graph rocclr fillBuffer costs ~115 us regardless of size — r10/r11 PMC)
  zfill_kernel<<<dim3(kWsZeroF4 / 256), blk, 0, stream>>>((float4*)ws);

  mean_kernel<<<dim3(32, kB), blk, 0, stream>>>(coords, dsum);
  maxnorm_kernel<<<dim3(32, kB), blk, 0, stream>>>(coords, dsum, maxbits);

  int chunkB = 0;
  for (int c = kB; c >= 1; c >>= 1) {
    if (ws_size >= wsNeed(c)) { chunkB = c; break; }
  }

  if (chunkB) {
    hash_nc_kernel<<<dim3(pblk, kB), blk, 0, stream>>>(coords, dsum, maxbits, out_nc,
                                                       hashes, lr, counts);
    scan_reduce<<<dim3(256), blk, 0, stream>>>(counts, bsum3);
    scan_bsum<<<dim3(1), blk, 0, stream>>>(bsum3);
    scan_write<<<dim3(256), blk, 0, stream>>>(counts, bsum3, offsets, Llist, Hlist, nlh);

    // zeros for empty voxels via fast custom fill
    zfill_kernel<<<dim3((unsigned)(kGridElems / 4 / 256)), blk, 0, stream>>>((float4*)out);

    for (int b0 = 0; b0 < kB; b0 += chunkB) {
      tr_kernel<<<dim3(kN / 32, chunkB), blk, 0, stream>>>(feat, hashes, lr, offsets,
                                                           feat_t, b0);
      gather_light<<<dim3(kNV / 16), blk, 0, stream>>>(feat_t, offsets, Llist, nlh, out,
                                                       b0, chunkB);
      gather_heavy<<<dim3(kMaxHeavy), blk, 0, stream>>>(feat_t, offsets, Hlist, nlh, out,
                                                        b0, chunkB);
    }
  } else {
    // fallback: direct atomics into final layout
    zfill_kernel<<<dim3((unsigned)(kGridElems / 4 / 256)), blk, 0, stream>>>((float4*)out);
    scatter_direct<<<dim3(pblk, kB), blk, 0, stream>>>(feat, coords, dsum, maxbits, out,
                                                       out_nc, counts);
    const size_t vec4 = kGridElems / 4;
    divide_inplace<<<dim3((unsigned)((vec4 + 255) / 256)), blk, 0, stream>>>(out, counts);
  }
}

// Round 13
// 194.509 us; speedup vs baseline: 1.8205x; 1.2543x over previous
//
#include <hip/hip_runtime.h>

namespace {
constexpr int kB = 8;
constexpr int kC = 64;
constexpr int kN = 100000;
constexpr int kR = 32;
constexpr int kR3 = kR * kR * kR;                     // 32768
constexpr size_t kGridElems = (size_t)kB * kC * kR3;  // 16,777,216
constexpr int kNV = kB * kR3;                         // 262144 voxel bins
constexpr int kNQ = kNV / 4;                          // 65536
constexpr unsigned kTh = 32;                          // light/heavy row threshold
constexpr int kMaxHeavy = kB * kN / (int)(kTh + 1) + 2;  // <= 24244

// ws layout (bytes)
constexpr size_t kDsumOff = 0;                                 // 192 B
constexpr size_t kMaxOff = 192;                                // 32 B
constexpr size_t kNlhOff = 240;                                // 2 uints
constexpr size_t kBsum3Off = 1024;                             // uint4[256] = 4 KB
constexpr size_t kCountsOff = 8192;                            // 1 MB
constexpr size_t kOffsetsOff = kCountsOff + (size_t)kNV * 4;   // (kNV+64) uints
constexpr size_t kLlistOff = kOffsetsOff + (size_t)(kNV + 64) * 4;  // u32 x kNV
constexpr size_t kHlistOff = kLlistOff + (size_t)kNV * 4;      // u32 x kNQ
constexpr size_t kHashOff = kHlistOff + (size_t)kNQ * 4;       // u16 x 800000
constexpr size_t kLrOff = kHashOff + (size_t)kB * kN * 2;      // u32 x 800000
constexpr size_t kFeatTOff = kLrOff + (size_t)kB * kN * 4;     // bf16 rows
inline size_t wsNeed(int chunkB) { return kFeatTOff + (size_t)chunkB * kN * kC * 2; }
// zero sizes (float4 units)
constexpr size_t kWsZeroBytes = kCountsOff + (size_t)kNV * 4;  // 1,056,768
constexpr unsigned kWsZeroBlks = (unsigned)(kWsZeroBytes / 16 / 256);   // 258
constexpr unsigned kOutZeroBlks = (unsigned)(kGridElems * 4 / 16 / 256);  // 16384
}  // namespace

__device__ __forceinline__ void f4add(float4& a, const float4& f) {
  a.x += f.x; a.y += f.y; a.z += f.z; a.w += f.w;
}
__device__ __forceinline__ unsigned short f2bf(float f) {
  const unsigned u = __float_as_uint(f);
  const unsigned rnd = 0x7FFFu + ((u >> 16) & 1u);
  return (unsigned short)((u + rnd) >> 16);
}
__device__ __forceinline__ float bf2f(unsigned short h) {
  return __uint_as_float((unsigned)h << 16);
}
__device__ __forceinline__ void bf4add(float4& a, const ushort4 f) {
  a.x += bf2f(f.x); a.y += bf2f(f.y); a.z += bf2f(f.z); a.w += bf2f(f.w);
}

// ---- one-dispatch zero fill: out grid (16384 blks) + ws header (258 blks) ----
__global__ __launch_bounds__(256) void zfill2_kernel(float4* __restrict__ out,
                                                     float4* __restrict__ ws) {
  const float4 z = make_float4(0.f, 0.f, 0.f, 0.f);
  const unsigned i = blockIdx.x;
  if (i < kOutZeroBlks)
    out[(size_t)i * 256 + threadIdx.x] = z;
  else
    ws[(size_t)(i - kOutZeroBlks) * 256 + threadIdx.x] = z;
}

// ---------------- Kernel A: per-batch coordinate sums (double) ----------------
__global__ __launch_bounds__(256) void mean_kernel(const float* __restrict__ coords,
                                                   double* __restrict__ dsum) {
  const int b = blockIdx.y;
  const int tid = blockIdx.x * blockDim.x + threadIdx.x;
  const int stride = gridDim.x * blockDim.x;
  const float* cb = coords + (size_t)b * 3 * kN;
  double s0 = 0.0, s1 = 0.0, s2 = 0.0;
  for (int n = tid; n < kN; n += stride) {
    s0 += (double)cb[n];
    s1 += (double)cb[kN + n];
    s2 += (double)cb[2 * kN + n];
  }
  __shared__ double sh[3][256];
  sh[0][threadIdx.x] = s0;
  sh[1][threadIdx.x] = s1;
  sh[2][threadIdx.x] = s2;
  __syncthreads();
  for (int off = 128; off > 0; off >>= 1) {
    if (threadIdx.x < (unsigned)off) {
      sh[0][threadIdx.x] += sh[0][threadIdx.x + off];
      sh[1][threadIdx.x] += sh[1][threadIdx.x + off];
      sh[2][threadIdx.x] += sh[2][threadIdx.x + off];
    }
    __syncthreads();
  }
  if (threadIdx.x == 0) {
    atomicAdd(&dsum[b * 3 + 0], sh[0][0]);
    atomicAdd(&dsum[b * 3 + 1], sh[1][0]);
    atomicAdd(&dsum[b * 3 + 2], sh[2][0]);
  }
}

// ------------- Kernel B: per-batch max of squared norm (f32, no fma) ----------
__global__ __launch_bounds__(256) void maxnorm_kernel(const float* __restrict__ coords,
                                                      const double* __restrict__ dsum,
                                                      unsigned* __restrict__ maxbits) {
#pragma clang fp contract(off)
  const int b = blockIdx.y;
  const int tid = blockIdx.x * blockDim.x + threadIdx.x;
  const int stride = gridDim.x * blockDim.x;
  const float* cb = coords + (size_t)b * 3 * kN;
  const float m0 = (float)(dsum[b * 3 + 0] / (double)kN);
  const float m1 = (float)(dsum[b * 3 + 1] / (double)kN);
  const float m2 = (float)(dsum[b * 3 + 2] / (double)kN);
  float mx = 0.0f;
  for (int n = tid; n < kN; n += stride) {
    float x = cb[n] - m0;
    float y = cb[kN + n] - m1;
    float z = cb[2 * kN + n] - m2;
    float sx = x * x;
    float sy = y * y;
    float sz = z * z;
    float s = (sx + sy) + sz;  // match numpy's non-fused order
    mx = fmaxf(mx, s);
  }
  __shared__ float sh[256];
  sh[threadIdx.x] = mx;
  __syncthreads();
  for (int off = 128; off > 0; off >>= 1) {
    if (threadIdx.x < (unsigned)off)
      sh[threadIdx.x] = fmaxf(sh[threadIdx.x], sh[threadIdx.x + off]);
    __syncthreads();
  }
  if (threadIdx.x == 0) atomicMax(&maxbits[b], __float_as_uint(sh[0]));
}

// ---------- common per-point geometry: returns h[4], writes norm_coords ------
__device__ __forceinline__ void point_geom(const float* __restrict__ coords,
                                           const double* __restrict__ dsum,
                                           const unsigned* __restrict__ maxbits,
                                           float* __restrict__ out_nc, int b, int n0,
                                           int h[4]) {
#pragma clang fp contract(off)
  const float m0 = (float)(dsum[b * 3 + 0] / (double)kN);
  const float m1 = (float)(dsum[b * 3 + 1] / (double)kN);
  const float m2 = (float)(dsum[b * 3 + 2] / (double)kN);
  const float scale = 2.0f * sqrtf(__uint_as_float(maxbits[b]));

  const float* cb = coords + (size_t)b * 3 * kN;
  const float4 cx = *(const float4*)(cb + n0);
  const float4 cy = *(const float4*)(cb + kN + n0);
  const float4 cz = *(const float4*)(cb + 2 * kN + n0);

  float xa[4] = {cx.x, cx.y, cx.z, cx.w};
  float ya[4] = {cy.x, cy.y, cy.z, cy.w};
  float za[4] = {cz.x, cz.y, cz.z, cz.w};
  float vx[4], vy[4], vz[4];
#pragma unroll
  for (int k = 0; k < 4; ++k) {
    float tx = (xa[k] - m0) / scale + 0.5f;
    float ty = (ya[k] - m1) / scale + 0.5f;
    float tz = (za[k] - m2) / scale + 0.5f;
    vx[k] = fminf(fmaxf(tx * 32.0f, 0.0f), 31.0f);
    vy[k] = fminf(fmaxf(ty * 32.0f, 0.0f), 31.0f);
    vz[k] = fminf(fmaxf(tz * 32.0f, 0.0f), 31.0f);
    int ix = (int)rintf(vx[k]);
    int iy = (int)rintf(vy[k]);
    int iz = (int)rintf(vz[k]);
    h[k] = ix * (kR * kR) + iy * kR + iz;
  }
  float* nb = out_nc + (size_t)b * 3 * kN;
  *(float4*)(nb + n0) = make_float4(vx[0], vx[1], vx[2], vx[3]);
  *(float4*)(nb + kN + n0) = make_float4(vy[0], vy[1], vy[2], vy[3]);
  *(float4*)(nb + 2 * kN + n0) = make_float4(vz[0], vz[1], vz[2], vz[3]);
}

// - Kernel C: hash + nc + count histogram + local rank (800k uint atomics) ----
__global__ __launch_bounds__(256) void hash_nc_kernel(
    const float* __restrict__ coords, const double* __restrict__ dsum,
    const unsigned* __restrict__ maxbits, float* __restrict__ out_nc,
    unsigned short* __restrict__ hashes, unsigned* __restrict__ lr,
    unsigned* __restrict__ counts) {
  const int b = blockIdx.y;
  const int n0 = (blockIdx.x * 256 + threadIdx.x) * 4;
  if (n0 >= kN) return;
  int h[4];
  point_geom(coords, dsum, maxbits, out_nc, b, n0, h);
  ushort4 h4;
  h4.x = (unsigned short)h[0];
  h4.y = (unsigned short)h[1];
  h4.z = (unsigned short)h[2];
  h4.w = (unsigned short)h[3];
  *(ushort4*)(hashes + (size_t)b * kN + n0) = h4;
  unsigned* cnt = counts + (size_t)b * kR3;
  uint4 l;
  l.x = atomicAdd(&cnt[h[0]], 1u);
  l.y = atomicAdd(&cnt[h[1]], 1u);
  l.z = atomicAdd(&cnt[h[2]], 1u);
  l.w = atomicAdd(&cnt[h[3]], 1u);
  *(uint4*)(lr + (size_t)b * kN + n0) = l;
}

// ------------ fused scan (3 kernels): offsets + light/heavy lists ------------
__global__ __launch_bounds__(256) void scan_reduce(const unsigned* __restrict__ counts,
                                                   uint4* __restrict__ bsum3) {
  __shared__ unsigned sht[256], shl[256], shh[256];
  const int t = threadIdx.x;
  const uint4 c = ((const uint4*)counts)[blockIdx.x * 256 + t];
  const unsigned cnt[4] = {c.x, c.y, c.z, c.w};
  unsigned tot = 0, lt = 0, ht = 0;
#pragma unroll
  for (int k = 0; k < 4; ++k) {
    tot += cnt[k];
    lt += (cnt[k] >= 1u && cnt[k] <= kTh) ? 1u : 0u;
    ht += (cnt[k] > kTh) ? 1u : 0u;
  }
  sht[t] = tot;
  shl[t] = lt;
  shh[t] = ht;
  __syncthreads();
  for (int off = 128; off > 0; off >>= 1) {
    if (t < off) {
      sht[t] += sht[t + off];
      shl[t] += shl[t + off];
      shh[t] += shh[t + off];
    }
    __syncthreads();
  }
  if (t == 0) bsum3[blockIdx.x] = make_uint4(sht[0], shl[0], shh[0], 0u);
}

__global__ __launch_bounds__(256) void scan_bsum(uint4* __restrict__ bsum3) {
  __shared__ unsigned sht[256], shl[256], shh[256];
  const int t = threadIdx.x;
  const uint4 v = bsum3[t];
  sht[t] = v.x;
  shl[t] = v.y;
  shh[t] = v.z;
  __syncthreads();
  for (int d = 1; d < 256; d <<= 1) {
    const unsigned xt = (t >= d) ? sht[t - d] : 0u;
    const unsigned xl = (t >= d) ? shl[t - d] : 0u;
    const unsigned xh = (t >= d) ? shh[t - d] : 0u;
    __syncthreads();
    sht[t] += xt;
    shl[t] += xl;
    shh[t] += xh;
    __syncthreads();
  }
  bsum3[t] = make_uint4(sht[t] - v.x, shl[t] - v.y, shh[t] - v.z, 0u);  // exclusive
}

__global__ __launch_bounds__(256) void scan_write(const unsigned* __restrict__ counts,
                                                  const uint4* __restrict__ bsum3,
                                                  unsigned* __restrict__ offsets,
                                                  unsigned* __restrict__ Llist,
                                                  unsigned* __restrict__ Hlist,
                                                  unsigned* __restrict__ nlh) {
  __shared__ unsigned sht[256], shl[256], shh[256];
  const int t = threadIdx.x;
  const int gi = blockIdx.x * 256 + t;
  const int v0 = gi * 4;
  const uint4 c = ((const uint4*)counts)[gi];
  const unsigned cnt[4] = {c.x, c.y, c.z, c.w};
  unsigned lf[4], hf[4], tot = 0, lt = 0, ht = 0;
#pragma unroll
  for (int k = 0; k < 4; ++k) {
    lf[k] = (cnt[k] >= 1u && cnt[k] <= kTh) ? 1u : 0u;
    hf[k] = (cnt[k] > kTh) ? 1u : 0u;
    tot += cnt[k];
    lt += lf[k];
    ht += hf[k];
  }
  sht[t] = tot;
  shl[t] = lt;
  shh[t] = ht;
  __syncthreads();
  for (int d = 1; d < 256; d <<= 1) {
    const unsigned xt = (t >= d) ? sht[t - d] : 0u;
    const unsigned xl = (t >= d) ? shl[t - d] : 0u;
    const unsigned xh = (t >= d) ? shh[t - d] : 0u;
    __syncthreads();
    sht[t] += xt;
    shl[t] += xl;
    shh[t] += xh;
    __syncthreads();
  }
  const uint4 bs = bsum3[blockIdx.x];
  const unsigned base = bs.x + sht[t] - tot;
  uint4 o;
  o.x = base;
  o.y = o.x + cnt[0];
  o.z = o.y + cnt[1];
  o.w = o.z + cnt[2];
  ((uint4*)offsets)[gi] = o;
  if (gi == kNV / 4 - 1) offsets[kNV] = o.w + cnt[3];  // total = B*N
  unsigned lbase = bs.y + shl[t] - lt;
  unsigned hbase = bs.z + shh[t] - ht;
#pragma unroll
  for (int k = 0; k < 4; ++k) {
    if (lf[k]) Llist[lbase++] = (unsigned)(v0 + k);
    if (hf[k]) Hlist[hbase++] = (unsigned)(v0 + k);
  }
  if (blockIdx.x == 255 && t == 255) {
    nlh[0] = lbase;
    nlh[1] = hbase;
  }
}

// - Kernel F: transpose feat (B,C,N) -> SORTED bf16 rows feat_t[off+lr][c] ----
__global__ __launch_bounds__(256) void tr_kernel(const float* __restrict__ feat,
                                                 const unsigned short* __restrict__ hashes,
                                                 const unsigned* __restrict__ lr,
                                                 const unsigned* __restrict__ offsets,
                                                 unsigned short* __restrict__ feat_t,
                                                 int b0) {
  const int b2 = blockIdx.y;
  const int b = b0 + b2;
  const int n0 = blockIdx.x * 32;
  __shared__ float tile[64][33];
  __shared__ unsigned shr[32];
  if (threadIdx.x < 32) {
    const int n = n0 + threadIdx.x;
    const unsigned hh = hashes[(size_t)b * kN + n];
    const unsigned l = lr[(size_t)b * kN + n];
    shr[threadIdx.x] = offsets[(size_t)b * kR3 + hh] + l - (unsigned)b0 * (unsigned)kN;
  }
  const float* fb = feat + (size_t)b * kC * kN;
#pragma unroll
  for (int j = 0; j < 2; ++j) {
    const int idx = j * 256 + threadIdx.x;  // 0..511
    const int c = idx >> 3;
    const int q = idx & 7;
    const float4 v = *(const float4*)(fb + (size_t)c * kN + n0 + q * 4);
    tile[c][q * 4 + 0] = v.x;
    tile[c][q * 4 + 1] = v.y;
    tile[c][q * 4 + 2] = v.z;
    tile[c][q * 4 + 3] = v.w;
  }
  __syncthreads();
#pragma unroll
  for (int j = 0; j < 2; ++j) {
    const int idx = j * 256 + threadIdx.x;  // 0..511
    const int n = idx >> 4;
    const int cq = idx & 15;
    ushort4 w;
    w.x = f2bf(tile[cq * 4 + 0][n]);
    w.y = f2bf(tile[cq * 4 + 1][n]);
    w.z = f2bf(tile[cq * 4 + 2][n]);
    w.w = f2bf(tile[cq * 4 + 3][n]);
    const size_t row = (size_t)shr[n];
    *(ushort4*)(feat_t + row * kC + cq * 4) = w;
  }
}

// --- Kernel G1: light voxels (1..kTh rows): wave handles 4 list entries ------
__global__ __launch_bounds__(256) void gather_light(const unsigned short* __restrict__ feat_t,
                                                    const unsigned* __restrict__ offsets,
                                                    const unsigned* __restrict__ Llist,
                                                    const unsigned* __restrict__ nlh,
                                                    float* __restrict__ out, int b0,
                                                    int chunkB) {
  const unsigned nl = nlh[0];
  const int wid = blockIdx.x * 4 + (threadIdx.x >> 6);
  const int lane = threadIdx.x & 63;
  const int p = lane >> 4;   // list slot 0..3
  const int cq = lane & 15;  // channel quad
  const unsigned i0 = (unsigned)wid * 4;
  if (i0 >= nl) return;
  const unsigned ip = i0 + (unsigned)p;
  bool act = ip < nl;
  const unsigned v = Llist[act ? ip : i0];
  const unsigned vlo = (unsigned)b0 * (unsigned)kR3;
  const unsigned vhi = (unsigned)(b0 + chunkB) * (unsigned)kR3;
  act = act && (v >= vlo) && (v < vhi);
  const unsigned s = offsets[v];
  unsigned e = offsets[v + 1];
  if (!act) e = s;
  const unsigned rb = (unsigned)b0 * (unsigned)kN;
  const unsigned short* ft = feat_t + cq * 4;
  float4 acc = make_float4(0.f, 0.f, 0.f, 0.f);
  unsigned r = s;
  for (; r + 2 <= e; r += 2) {
    const ushort4 f0 = *(const ushort4*)(ft + (size_t)(r - rb) * kC);
    const ushort4 f1 = *(const ushort4*)(ft + (size_t)(r + 1 - rb) * kC);
    bf4add(acc, f0);
    bf4add(acc, f1);
  }
  if (r < e) {
    const ushort4 f0 = *(const ushort4*)(ft + (size_t)(r - rb) * kC);
    bf4add(acc, f0);
  }
  if (act) {
    const float k = (float)(e - s);
    const int b = (int)(v >> 15);
    const int h = (int)(v & (kR3 - 1));
    float* ob = out + ((size_t)b * kC + cq * 4) * kR3 + h;
    ob[0] = acc.x / k;
    ob[(size_t)kR3] = acc.y / k;
    ob[(size_t)2 * kR3] = acc.z / k;
    ob[(size_t)3 * kR3] = acc.w / k;
  }
}

// --- Kernel G2: heavy voxels (>kTh rows): one 256-thread block per voxel -----
__global__ __launch_bounds__(256) void gather_heavy(const unsigned short* __restrict__ feat_t,
                                                    const unsigned* __restrict__ offsets,
                                                    const unsigned* __restrict__ Hlist,
                                                    const unsigned* __restrict__ nlh,
                                                    float* __restrict__ out, int b0,
                                                    int chunkB) {
  const unsigned nh = nlh[1];
  if (blockIdx.x >= nh) return;
  const unsigned v = Hlist[blockIdx.x];
  const unsigned vlo = (unsigned)b0 * (unsigned)kR3;
  const unsigned vhi = (unsigned)(b0 + chunkB) * (unsigned)kR3;
  if (v < vlo || v >= vhi) return;
  const unsigned s = offsets[v];
  const unsigned e = offsets[v + 1];
  const int slot = threadIdx.x >> 4;  // row slot 0..15
  const int cq = threadIdx.x & 15;    // channel quad
  const unsigned rb = (unsigned)b0 * (unsigned)kN;
  float4 acc = make_float4(0.f, 0.f, 0.f, 0.f);
  for (unsigned r = s + (unsigned)slot; r < e; r += 16) {
    const ushort4 f = *(const ushort4*)(feat_t + (size_t)(r - rb) * kC + cq * 4);
    bf4add(acc, f);
  }
  __shared__ float sh[16][64];
  sh[slot][cq * 4 + 0] = acc.x;
  sh[slot][cq * 4 + 1] = acc.y;
  sh[slot][cq * 4 + 2] = acc.z;
  sh[slot][cq * 4 + 3] = acc.w;
  __syncthreads();
  if (threadIdx.x < 64) {
    const int c = threadIdx.x;
    float t = 0.f;
#pragma unroll
    for (int k = 0; k < 16; ++k) t += sh[k][c];
    const int b = (int)(v >> 15);
    const int h = (int)(v & (kR3 - 1));
    out[((size_t)b * kC + c) * kR3 + h] = t / (float)(e - s);
  }
}

// --------------- Fallback: direct atomics into out (b,c,h) -------------------
__global__ __launch_bounds__(256) void scatter_direct(
    const float* __restrict__ feat, const float* __restrict__ coords,
    const double* __restrict__ dsum, const unsigned* __restrict__ maxbits,
    float* __restrict__ gridsum, float* __restrict__ out_nc,
    unsigned* __restrict__ counts) {
  const int b = blockIdx.y;
  const int n0 = (blockIdx.x * 256 + threadIdx.x) * 4;
  if (n0 >= kN) return;
  int h[4];
  point_geom(coords, dsum, maxbits, out_nc, b, n0, h);
  unsigned* cnt = counts + (size_t)b * kR3;
  atomicAdd(&cnt[h[0]], 1u);
  atomicAdd(&cnt[h[1]], 1u);
  atomicAdd(&cnt[h[2]], 1u);
  atomicAdd(&cnt[h[3]], 1u);
  const float* fb = feat + (size_t)b * kC * kN + n0;
  float* gb = gridsum + (size_t)b * kC * kR3;
#pragma unroll 8
  for (int c = 0; c < kC; ++c) {
    const float4 f = *(const float4*)(fb + (size_t)c * kN);
    float* g = gb + (size_t)c * kR3;
    unsafeAtomicAdd(g + h[0], f.x);
    unsafeAtomicAdd(g + h[1], f.y);
    unsafeAtomicAdd(g + h[2], f.z);
    unsafeAtomicAdd(g + h[3], f.w);
  }
}

__global__ __launch_bounds__(256) void divide_inplace(float* __restrict__ grid,
                                                      const unsigned* __restrict__ counts) {
  const size_t e = ((size_t)blockIdx.x * blockDim.x + threadIdx.x) * 4;
  if (e >= kGridElems) return;
  const int h = (int)(e & (size_t)(kR3 - 1));
  const int b = (int)(e >> 21);
  const uint4 cnt = *(const uint4*)(counts + (size_t)b * kR3 + h);
  float4 g = *(float4*)(grid + e);
  g.x = g.x / (float)(cnt.x > 1u ? cnt.x : 1u);
  g.y = g.y / (float)(cnt.y > 1u ? cnt.y : 1u);
  g.z = g.z / (float)(cnt.z > 1u ? cnt.z : 1u);
  g.w = g.w / (float)(cnt.w > 1u ? cnt.w : 1u);
  *(float4*)(grid + e) = g;
}

extern "C" void kernel_launch(void* const* d_in, const int* in_sizes, int n_in,
                              void* d_out, int out_size, void* d_ws, size_t ws_size,
                              hipStream_t stream) {
  const float* feat = (const float*)d_in[0];    // (8, 64, 100000)
  const float* coords = (const float*)d_in[1];  // (8, 3, 100000)
  float* out = (float*)d_out;
  float* out_nc = out + kGridElems;  // (8, 3, 100000)

  char* ws = (char*)d_ws;
  double* dsum = (double*)(ws + kDsumOff);
  unsigned* maxbits = (unsigned*)(ws + kMaxOff);
  unsigned* nlh = (unsigned*)(ws + kNlhOff);
  uint4* bsum3 = (uint4*)(ws + kBsum3Off);
  unsigned* counts = (unsigned*)(ws + kCountsOff);
  unsigned* offsets = (unsigned*)(ws + kOffsetsOff);
  unsigned* Llist = (unsigned*)(ws + kLlistOff);
  unsigned* Hlist = (unsigned*)(ws + kHlistOff);
  unsigned short* hashes = (unsigned short*)(ws + kHashOff);
  unsigned* lr = (unsigned*)(ws + kLrOff);
  unsigned short* feat_t = (unsigned short*)(ws + kFeatTOff);

  const dim3 blk(256);
  const int pblk = (kN / 4 + 255) / 256;  // 98 point-blocks per batch

  int chunkB = 0;
  for (int c = kB; c >= 1; c >>= 1) {
    if (ws_size >= wsNeed(c)) { chunkB = c; break; }
  }

  if (chunkB) {
    // one dispatch zeroes both the out grid and the ws header+counts
    zfill2_kernel<<<dim3(kOutZeroBlks + kWsZeroBlks), blk, 0, stream>>>((float4*)out,
                                                                        (float4*)ws);
    mean_kernel<<<dim3(32, kB), blk, 0, stream>>>(coords, dsum);
    maxnorm_kernel<<<dim3(32, kB), blk, 0, stream>>>(coords, dsum, maxbits);
    hash_nc_kernel<<<dim3(pblk, kB), blk, 0, stream>>>(coords, dsum, maxbits, out_nc,
                                                       hashes, lr, counts);
    scan_reduce<<<dim3(256), blk, 0, stream>>>(counts, bsum3);
    scan_bsum<<<dim3(1), blk, 0, stream>>>(bsum3);
    scan_write<<<dim3(256), blk, 0, stream>>>(counts, bsum3, offsets, Llist, Hlist, nlh);

    for (int b0 = 0; b0 < kB; b0 += chunkB) {
      tr_kernel<<<dim3(kN / 32, chunkB), blk, 0, stream>>>(feat, hashes, lr, offsets,
                                                           feat_t, b0);
      gather_light<<<dim3(kNV / 16), blk, 0, stream>>>(feat_t, offsets, Llist, nlh, out,
                                                       b0, chunkB);
      gather_heavy<<<dim3(kMaxHeavy), blk, 0, stream>>>(feat_t, offsets, Hlist, nlh, out,
                                                        b0, chunkB);
    }
  } else {
    // fallback: direct atomics into final layout (f32, no bf16 ws needed)
    zfill2_kernel<<<dim3(kOutZeroBlks + kWsZeroBlks), blk, 0, stream>>>((float4*)out,
                                                                        (float4*)ws);
    mean_kernel<<<dim3(32, kB), blk, 0, stream>>>(coords, dsum);
    maxnorm_kernel<<<dim3(32, kB), blk, 0, stream>>>(coords, dsum, maxbits);
    scatter_direct<<<dim3(pblk, kB), blk, 0, stream>>>(feat, coords, dsum, maxbits, out,
                                                       out_nc, counts);
    const size_t vec4 = kGridElems / 4;
    divide_inplace<<<dim3((unsigned)((vec4 + 255) / 256)), blk, 0, stream>>>(out, counts);
  }
}

// Round 14
// 179.906 us; speedup vs baseline: 1.9683x; 1.0812x over previous
//
#include <hip/hip_runtime.h>

namespace {
constexpr int kB = 8;
constexpr int kC = 64;
constexpr int kN = 100000;
constexpr int kR = 32;
constexpr int kR3 = kR * kR * kR;                     // 32768
constexpr size_t kGridElems = (size_t)kB * kC * kR3;  // 16,777,216
constexpr int kNV = kB * kR3;                         // 262144 voxel bins
constexpr int kNQ = kNV / 4;                          // 65536
constexpr unsigned kTh = 32;                          // light/heavy row threshold
constexpr int kMaxHeavy = kB * kN / (int)(kTh + 1) + 2;  // <= 24244
constexpr int kLightBlks = kNV / 16;                  // 16384

// ws layout (bytes)
constexpr size_t kDpartOff = 0;                                // 256 blk x 3 dbl = 6144
constexpr size_t kMeanfOff = 6144;                             // 24 floats
constexpr size_t kMaxOff = 6272;                               // 8 uints
constexpr size_t kNlhOff = 6336;                               // 2 uints
constexpr size_t kBsum3Off = 8192;                             // uint4[256] = 4 KB
constexpr size_t kCountsOff = 16384;                           // 1 MB
constexpr size_t kOffsetsOff = kCountsOff + (size_t)kNV * 4;   // (kNV+64) uints
constexpr size_t kLlistOff = kOffsetsOff + (size_t)(kNV + 64) * 4;  // u32 x kNV
constexpr size_t kHlistOff = kLlistOff + (size_t)kNV * 4;      // u32 x kNQ
constexpr size_t kHashOff = kHlistOff + (size_t)kNQ * 4;       // u16 x 800000
constexpr size_t kLrOff = kHashOff + (size_t)kB * kN * 2;      // u32 x 800000
constexpr size_t kFeatTOff = kLrOff + (size_t)kB * kN * 4;     // bf16 rows
inline size_t wsNeed(int chunkB) { return kFeatTOff + (size_t)chunkB * kN * kC * 2; }
// fused zero+mean geometry
constexpr unsigned kMeanBlks = 256;  // 32 blocks x 8 batches
constexpr unsigned kOutZeroBlks = (unsigned)(kGridElems * 4 / 16 / 256);  // 16384
constexpr unsigned kWsZeroF4 = (unsigned)((kCountsOff + (size_t)kNV * 4 - kMaxOff) / 16);
constexpr unsigned kWsZeroBlks = (kWsZeroF4 + 255) / 256;  // covers maxbits..counts end
}  // namespace

__device__ __forceinline__ void f4add(float4& a, const float4& f) {
  a.x += f.x; a.y += f.y; a.z += f.z; a.w += f.w;
}
__device__ __forceinline__ unsigned short f2bf(float f) {
  const unsigned u = __float_as_uint(f);
  const unsigned rnd = 0x7FFFu + ((u >> 16) & 1u);
  return (unsigned short)((u + rnd) >> 16);
}
__device__ __forceinline__ float bf2f(unsigned short h) {
  return __uint_as_float((unsigned)h << 16);
}
__device__ __forceinline__ void bf4add(float4& a, const ushort4 f) {
  a.x += bf2f(f.x); a.y += bf2f(f.y); a.z += bf2f(f.z); a.w += bf2f(f.w);
}

// --- Kernel A' (fused): mean partials (256 blks) || zero out || zero ws ------
__global__ __launch_bounds__(256) void zm_kernel(const float* __restrict__ coords,
                                                 double* __restrict__ dpart,
                                                 float4* __restrict__ outz,
                                                 float4* __restrict__ wsz) {
  const unsigned bx = blockIdx.x;
  if (bx < kMeanBlks) {
    const int b = (int)(bx >> 5);
    const int xb = (int)(bx & 31);
    const float* cb = coords + (size_t)b * 3 * kN;
    double s0 = 0.0, s1 = 0.0, s2 = 0.0;
    for (int n = xb * 256 + (int)threadIdx.x; n < kN; n += 8192) {
      s0 += (double)cb[n];
      s1 += (double)cb[kN + n];
      s2 += (double)cb[2 * kN + n];
    }
    __shared__ double sh[3][256];
    sh[0][threadIdx.x] = s0;
    sh[1][threadIdx.x] = s1;
    sh[2][threadIdx.x] = s2;
    __syncthreads();
    for (int off = 128; off > 0; off >>= 1) {
      if (threadIdx.x < (unsigned)off) {
        sh[0][threadIdx.x] += sh[0][threadIdx.x + off];
        sh[1][threadIdx.x] += sh[1][threadIdx.x + off];
        sh[2][threadIdx.x] += sh[2][threadIdx.x + off];
      }
      __syncthreads();
    }
    if (threadIdx.x == 0) {
      dpart[(size_t)bx * 3 + 0] = sh[0][0];
      dpart[(size_t)bx * 3 + 1] = sh[1][0];
      dpart[(size_t)bx * 3 + 2] = sh[2][0];
    }
  } else if (bx < kMeanBlks + kOutZeroBlks) {
    outz[(size_t)(bx - kMeanBlks) * 256 + threadIdx.x] =
        make_float4(0.f, 0.f, 0.f, 0.f);
  } else {
    const unsigned i = (bx - kMeanBlks - kOutZeroBlks) * 256 + threadIdx.x;
    if (i < kWsZeroF4) wsz[i] = make_float4(0.f, 0.f, 0.f, 0.f);
  }
}

// -- Kernel B: mean from partials (fixed order) + max sq-norm (f32, no fma) ---
__global__ __launch_bounds__(256) void maxnorm_kernel(const float* __restrict__ coords,
                                                      const double* __restrict__ dpart,
                                                      float* __restrict__ meanf,
                                                      unsigned* __restrict__ maxbits) {
#pragma clang fp contract(off)
  const int b = blockIdx.y;
  __shared__ float m[3];
  if (threadIdx.x == 0) {
    double s0 = 0.0, s1 = 0.0, s2 = 0.0;
    for (int j = 0; j < 32; ++j) {
      s0 += dpart[(size_t)(b * 32 + j) * 3 + 0];
      s1 += dpart[(size_t)(b * 32 + j) * 3 + 1];
      s2 += dpart[(size_t)(b * 32 + j) * 3 + 2];
    }
    m[0] = (float)(s0 / (double)kN);
    m[1] = (float)(s1 / (double)kN);
    m[2] = (float)(s2 / (double)kN);
    if (blockIdx.x == 0) {
      meanf[b * 3 + 0] = m[0];
      meanf[b * 3 + 1] = m[1];
      meanf[b * 3 + 2] = m[2];
    }
  }
  __syncthreads();
  const float m0 = m[0], m1 = m[1], m2 = m[2];
  const int tid = blockIdx.x * 256 + threadIdx.x;
  const int stride = gridDim.x * 256;
  const float* cb = coords + (size_t)b * 3 * kN;
  float mx = 0.0f;
  for (int n = tid; n < kN; n += stride) {
    float x = cb[n] - m0;
    float y = cb[kN + n] - m1;
    float z = cb[2 * kN + n] - m2;
    float sx = x * x;
    float sy = y * y;
    float sz = z * z;
    float s = (sx + sy) + sz;  // match numpy's non-fused order
    mx = fmaxf(mx, s);
  }
  __shared__ float sh[256];
  sh[threadIdx.x] = mx;
  __syncthreads();
  for (int off = 128; off > 0; off >>= 1) {
    if (threadIdx.x < (unsigned)off)
      sh[threadIdx.x] = fmaxf(sh[threadIdx.x], sh[threadIdx.x + off]);
    __syncthreads();
  }
  if (threadIdx.x == 0) atomicMax(&maxbits[b], __float_as_uint(sh[0]));
}

// ---------- common per-point geometry: returns h[4], writes norm_coords ------
__device__ __forceinline__ void point_geom(const float* __restrict__ coords,
                                           const float* __restrict__ meanf,
                                           const unsigned* __restrict__ maxbits,
                                           float* __restrict__ out_nc, int b, int n0,
                                           int h[4]) {
#pragma clang fp contract(off)
  const float m0 = meanf[b * 3 + 0];
  const float m1 = meanf[b * 3 + 1];
  const float m2 = meanf[b * 3 + 2];
  const float scale = 2.0f * sqrtf(__uint_as_float(maxbits[b]));

  const float* cb = coords + (size_t)b * 3 * kN;
  const float4 cx = *(const float4*)(cb + n0);
  const float4 cy = *(const float4*)(cb + kN + n0);
  const float4 cz = *(const float4*)(cb + 2 * kN + n0);

  float xa[4] = {cx.x, cx.y, cx.z, cx.w};
  float ya[4] = {cy.x, cy.y, cy.z, cy.w};
  float za[4] = {cz.x, cz.y, cz.z, cz.w};
  float vx[4], vy[4], vz[4];
#pragma unroll
  for (int k = 0; k < 4; ++k) {
    float tx = (xa[k] - m0) / scale + 0.5f;
    float ty = (ya[k] - m1) / scale + 0.5f;
    float tz = (za[k] - m2) / scale + 0.5f;
    vx[k] = fminf(fmaxf(tx * 32.0f, 0.0f), 31.0f);
    vy[k] = fminf(fmaxf(ty * 32.0f, 0.0f), 31.0f);
    vz[k] = fminf(fmaxf(tz * 32.0f, 0.0f), 31.0f);
    int ix = (int)rintf(vx[k]);
    int iy = (int)rintf(vy[k]);
    int iz = (int)rintf(vz[k]);
    h[k] = ix * (kR * kR) + iy * kR + iz;
  }
  float* nb = out_nc + (size_t)b * 3 * kN;
  *(float4*)(nb + n0) = make_float4(vx[0], vx[1], vx[2], vx[3]);
  *(float4*)(nb + kN + n0) = make_float4(vy[0], vy[1], vy[2], vy[3]);
  *(float4*)(nb + 2 * kN + n0) = make_float4(vz[0], vz[1], vz[2], vz[3]);
}

// - Kernel C: hash + nc + count histogram + local rank (800k uint atomics) ----
__global__ __launch_bounds__(256) void hash_nc_kernel(
    const float* __restrict__ coords, const float* __restrict__ meanf,
    const unsigned* __restrict__ maxbits, float* __restrict__ out_nc,
    unsigned short* __restrict__ hashes, unsigned* __restrict__ lr,
    unsigned* __restrict__ counts) {
  const int b = blockIdx.y;
  const int n0 = (blockIdx.x * 256 + threadIdx.x) * 4;
  if (n0 >= kN) return;
  int h[4];
  point_geom(coords, meanf, maxbits, out_nc, b, n0, h);
  ushort4 h4;
  h4.x = (unsigned short)h[0];
  h4.y = (unsigned short)h[1];
  h4.z = (unsigned short)h[2];
  h4.w = (unsigned short)h[3];
  *(ushort4*)(hashes + (size_t)b * kN + n0) = h4;
  unsigned* cnt = counts + (size_t)b * kR3;
  uint4 l;
  l.x = atomicAdd(&cnt[h[0]], 1u);
  l.y = atomicAdd(&cnt[h[1]], 1u);
  l.z = atomicAdd(&cnt[h[2]], 1u);
  l.w = atomicAdd(&cnt[h[3]], 1u);
  *(uint4*)(lr + (size_t)b * kN + n0) = l;
}

// ------------- fused scan (2 kernels): offsets + light/heavy lists -----------
__global__ __launch_bounds__(256) void scan_reduce(const unsigned* __restrict__ counts,
                                                   uint4* __restrict__ bsum3) {
  __shared__ unsigned sht[256], shl[256], shh[256];
  const int t = threadIdx.x;
  const uint4 c = ((const uint4*)counts)[blockIdx.x * 256 + t];
  const unsigned cnt[4] = {c.x, c.y, c.z, c.w};
  unsigned tot = 0, lt = 0, ht = 0;
#pragma unroll
  for (int k = 0; k < 4; ++k) {
    tot += cnt[k];
    lt += (cnt[k] >= 1u && cnt[k] <= kTh) ? 1u : 0u;
    ht += (cnt[k] > kTh) ? 1u : 0u;
  }
  sht[t] = tot;
  shl[t] = lt;
  shh[t] = ht;
  __syncthreads();
  for (int off = 128; off > 0; off >>= 1) {
    if (t < off) {
      sht[t] += sht[t + off];
      shl[t] += shl[t + off];
      shh[t] += shh[t + off];
    }
    __syncthreads();
  }
  if (t == 0) bsum3[blockIdx.x] = make_uint4(sht[0], shl[0], shh[0], 0u);
}

__global__ __launch_bounds__(256) void scan_write(const unsigned* __restrict__ counts,
                                                  const uint4* __restrict__ bsum3,
                                                  unsigned* __restrict__ offsets,
                                                  unsigned* __restrict__ Llist,
                                                  unsigned* __restrict__ Hlist,
                                                  unsigned* __restrict__ nlh) {
  __shared__ unsigned sht[256], shl[256], shh[256];
  const int t = threadIdx.x;
  // phase 1: local scan of the 256 block totals for this block's exclusive base
  const uint4 bv = bsum3[t];
  sht[t] = bv.x;
  shl[t] = bv.y;
  shh[t] = bv.z;
  __syncthreads();
  for (int d = 1; d < 256; d <<= 1) {
    const unsigned xt = (t >= d) ? sht[t - d] : 0u;
    const unsigned xl = (t >= d) ? shl[t - d] : 0u;
    const unsigned xh = (t >= d) ? shh[t - d] : 0u;
    __syncthreads();
    sht[t] += xt;
    shl[t] += xl;
    shh[t] += xh;
    __syncthreads();
  }
  const unsigned bbt = (blockIdx.x > 0) ? sht[blockIdx.x - 1] : 0u;
  const unsigned bbl = (blockIdx.x > 0) ? shl[blockIdx.x - 1] : 0u;
  const unsigned bbh = (blockIdx.x > 0) ? shh[blockIdx.x - 1] : 0u;
  __syncthreads();
  // phase 2: in-block element scan
  const int gi = blockIdx.x * 256 + t;
  const int v0 = gi * 4;
  const uint4 c = ((const uint4*)counts)[gi];
  const unsigned cnt[4] = {c.x, c.y, c.z, c.w};
  unsigned lf[4], hf[4], tot = 0, lt = 0, ht = 0;
#pragma unroll
  for (int k = 0; k < 4; ++k) {
    lf[k] = (cnt[k] >= 1u && cnt[k] <= kTh) ? 1u : 0u;
    hf[k] = (cnt[k] > kTh) ? 1u : 0u;
    tot += cnt[k];
    lt += lf[k];
    ht += hf[k];
  }
  sht[t] = tot;
  shl[t] = lt;
  shh[t] = ht;
  __syncthreads();
  for (int d = 1; d < 256; d <<= 1) {
    const unsigned xt = (t >= d) ? sht[t - d] : 0u;
    const unsigned xl = (t >= d) ? shl[t - d] : 0u;
    const unsigned xh = (t >= d) ? shh[t - d] : 0u;
    __syncthreads();
    sht[t] += xt;
    shl[t] += xl;
    shh[t] += xh;
    __syncthreads();
  }
  const unsigned base = bbt + sht[t] - tot;
  uint4 o;
  o.x = base;
  o.y = o.x + cnt[0];
  o.z = o.y + cnt[1];
  o.w = o.z + cnt[2];
  ((uint4*)offsets)[gi] = o;
  if (gi == kNV / 4 - 1) offsets[kNV] = o.w + cnt[3];  // total = B*N
  unsigned lbase = bbl + shl[t] - lt;
  unsigned hbase = bbh + shh[t] - ht;
#pragma unroll
  for (int k = 0; k < 4; ++k) {
    if (lf[k]) Llist[lbase++] = (unsigned)(v0 + k);
    if (hf[k]) Hlist[hbase++] = (unsigned)(v0 + k);
  }
  if (blockIdx.x == 255 && t == 255) {
    nlh[0] = lbase;
    nlh[1] = hbase;
  }
}

// - Kernel F: transpose feat (B,C,N) -> SORTED bf16 rows feat_t[off+lr][c] ----
__global__ __launch_bounds__(256) void tr_kernel(const float* __restrict__ feat,
                                                 const unsigned short* __restrict__ hashes,
                                                 const unsigned* __restrict__ lr,
                                                 const unsigned* __restrict__ offsets,
                                                 unsigned short* __restrict__ feat_t,
                                                 int b0) {
  const int b2 = blockIdx.y;
  const int b = b0 + b2;
  const int n0 = blockIdx.x * 32;
  __shared__ float tile[64][33];
  __shared__ unsigned shr[32];
  if (threadIdx.x < 32) {
    const int n = n0 + threadIdx.x;
    const unsigned hh = hashes[(size_t)b * kN + n];
    const unsigned l = lr[(size_t)b * kN + n];
    shr[threadIdx.x] = offsets[(size_t)b * kR3 + hh] + l - (unsigned)b0 * (unsigned)kN;
  }
  const float* fb = feat + (size_t)b * kC * kN;
#pragma unroll
  for (int j = 0; j < 2; ++j) {
    const int idx = j * 256 + threadIdx.x;  // 0..511
    const int c = idx >> 3;
    const int q = idx & 7;
    const float4 v = *(const float4*)(fb + (size_t)c * kN + n0 + q * 4);
    tile[c][q * 4 + 0] = v.x;
    tile[c][q * 4 + 1] = v.y;
    tile[c][q * 4 + 2] = v.z;
    tile[c][q * 4 + 3] = v.w;
  }
  __syncthreads();
#pragma unroll
  for (int j = 0; j < 2; ++j) {
    const int idx = j * 256 + threadIdx.x;  // 0..511
    const int n = idx >> 4;
    const int cq = idx & 15;
    ushort4 w;
    w.x = f2bf(tile[cq * 4 + 0][n]);
    w.y = f2bf(tile[cq * 4 + 1][n]);
    w.z = f2bf(tile[cq * 4 + 2][n]);
    w.w = f2bf(tile[cq * 4 + 3][n]);
    const size_t row = (size_t)shr[n];
    *(ushort4*)(feat_t + row * kC + cq * 4) = w;
  }
}

// ---- Kernel G (fused): light blocks [0,kLightBlks), heavy blocks after ------
__global__ __launch_bounds__(256) void gather_kernel(const unsigned short* __restrict__ feat_t,
                                                     const unsigned* __restrict__ offsets,
                                                     const unsigned* __restrict__ Llist,
                                                     const unsigned* __restrict__ Hlist,
                                                     const unsigned* __restrict__ nlh,
                                                     float* __restrict__ out, int b0,
                                                     int chunkB) {
  const unsigned rb = (unsigned)b0 * (unsigned)kN;
  const unsigned vlo = (unsigned)b0 * (unsigned)kR3;
  const unsigned vhi = (unsigned)(b0 + chunkB) * (unsigned)kR3;

  if (blockIdx.x < (unsigned)kLightBlks) {
    // ---- light path: wave handles 4 list entries ----
    const unsigned nl = nlh[0];
    const int wid = blockIdx.x * 4 + (threadIdx.x >> 6);
    const int lane = threadIdx.x & 63;
    const int p = lane >> 4;   // list slot 0..3
    const int cq = lane & 15;  // channel quad
    const unsigned i0 = (unsigned)wid * 4;
    if (i0 >= nl) return;
    const unsigned ip = i0 + (unsigned)p;
    bool act = ip < nl;
    const unsigned v = Llist[act ? ip : i0];
    act = act && (v >= vlo) && (v < vhi);
    const unsigned s = offsets[v];
    unsigned e = offsets[v + 1];
    if (!act) e = s;
    const unsigned short* ft = feat_t + cq * 4;
    float4 acc = make_float4(0.f, 0.f, 0.f, 0.f);
    unsigned r = s;
    for (; r + 2 <= e; r += 2) {
      const ushort4 f0 = *(const ushort4*)(ft + (size_t)(r - rb) * kC);
      const ushort4 f1 = *(const ushort4*)(ft + (size_t)(r + 1 - rb) * kC);
      bf4add(acc, f0);
      bf4add(acc, f1);
    }
    if (r < e) {
      const ushort4 f0 = *(const ushort4*)(ft + (size_t)(r - rb) * kC);
      bf4add(acc, f0);
    }
    if (act) {
      const float k = (float)(e - s);
      const int b = (int)(v >> 15);
      const int h = (int)(v & (kR3 - 1));
      float* ob = out + ((size_t)b * kC + cq * 4) * kR3 + h;
      ob[0] = acc.x / k;
      ob[(size_t)kR3] = acc.y / k;
      ob[(size_t)2 * kR3] = acc.z / k;
      ob[(size_t)3 * kR3] = acc.w / k;
    }
  } else {
    // ---- heavy path: one 256-thread block per voxel ----
    const unsigned hb = blockIdx.x - (unsigned)kLightBlks;
    const unsigned nh = nlh[1];
    if (hb >= nh) return;
    const unsigned v = Hlist[hb];
    if (v < vlo || v >= vhi) return;
    const unsigned s = offsets[v];
    const unsigned e = offsets[v + 1];
    const int slot = threadIdx.x >> 4;  // row slot 0..15
    const int cq = threadIdx.x & 15;    // channel quad
    float4 acc = make_float4(0.f, 0.f, 0.f, 0.f);
    for (unsigned r = s + (unsigned)slot; r < e; r += 16) {
      const ushort4 f = *(const ushort4*)(feat_t + (size_t)(r - rb) * kC + cq * 4);
      bf4add(acc, f);
    }
    __shared__ float sh[16][64];
    sh[slot][cq * 4 + 0] = acc.x;
    sh[slot][cq * 4 + 1] = acc.y;
    sh[slot][cq * 4 + 2] = acc.z;
    sh[slot][cq * 4 + 3] = acc.w;
    __syncthreads();
    if (threadIdx.x < 64) {
      const int c = threadIdx.x;
      float t = 0.f;
#pragma unroll
      for (int k = 0; k < 16; ++k) t += sh[k][c];
      const int b = (int)(v >> 15);
      const int h = (int)(v & (kR3 - 1));
      out[((size_t)b * kC + c) * kR3 + h] = t / (float)(e - s);
    }
  }
}

// --------------- Fallback: direct atomics into out (b,c,h) -------------------
__global__ __launch_bounds__(256) void scatter_direct(
    const float* __restrict__ feat, const float* __restrict__ coords,
    const float* __restrict__ meanf, const unsigned* __restrict__ maxbits,
    float* __restrict__ gridsum, float* __restrict__ out_nc,
    unsigned* __restrict__ counts) {
  const int b = blockIdx.y;
  const int n0 = (blockIdx.x * 256 + threadIdx.x) * 4;
  if (n0 >= kN) return;
  int h[4];
  point_geom(coords, meanf, maxbits, out_nc, b, n0, h);
  unsigned* cnt = counts + (size_t)b * kR3;
  atomicAdd(&cnt[h[0]], 1u);
  atomicAdd(&cnt[h[1]], 1u);
  atomicAdd(&cnt[h[2]], 1u);
  atomicAdd(&cnt[h[3]], 1u);
  const float* fb = feat + (size_t)b * kC * kN + n0;
  float* gb = gridsum + (size_t)b * kC * kR3;
#pragma unroll 8
  for (int c = 0; c < kC; ++c) {
    const float4 f = *(const float4*)(fb + (size_t)c * kN);
    float* g = gb + (size_t)c * kR3;
    unsafeAtomicAdd(g + h[0], f.x);
    unsafeAtomicAdd(g + h[1], f.y);
    unsafeAtomicAdd(g + h[2], f.z);
    unsafeAtomicAdd(g + h[3], f.w);
  }
}

__global__ __launch_bounds__(256) void divide_inplace(float* __restrict__ grid,
                                                      const unsigned* __restrict__ counts) {
  const size_t e = ((size_t)blockIdx.x * blockDim.x + threadIdx.x) * 4;
  if (e >= kGridElems) return;
  const int h = (int)(e & (size_t)(kR3 - 1));
  const int b = (int)(e >> 21);
  const uint4 cnt = *(const uint4*)(counts + (size_t)b * kR3 + h);
  float4 g = *(float4*)(grid + e);
  g.x = g.x / (float)(cnt.x > 1u ? cnt.x : 1u);
  g.y = g.y / (float)(cnt.y > 1u ? cnt.y : 1u);
  g.z = g.z / (float)(cnt.z > 1u ? cnt.z : 1u);
  g.w = g.w / (float)(cnt.w > 1u ? cnt.w : 1u);
  *(float4*)(grid + e) = g;
}

extern "C" void kernel_launch(void* const* d_in, const int* in_sizes, int n_in,
                              void* d_out, int out_size, void* d_ws, size_t ws_size,
                              hipStream_t stream) {
  const float* feat = (const float*)d_in[0];    // (8, 64, 100000)
  const float* coords = (const float*)d_in[1];  // (8, 3, 100000)
  float* out = (float*)d_out;
  float* out_nc = out + kGridElems;  // (8, 3, 100000)

  char* ws = (char*)d_ws;
  double* dpart = (double*)(ws + kDpartOff);
  float* meanf = (float*)(ws + kMeanfOff);
  unsigned* maxbits = (unsigned*)(ws + kMaxOff);
  unsigned* nlh = (unsigned*)(ws + kNlhOff);
  uint4* bsum3 = (uint4*)(ws + kBsum3Off);
  unsigned* counts = (unsigned*)(ws + kCountsOff);
  unsigned* offsets = (unsigned*)(ws + kOffsetsOff);
  unsigned* Llist = (unsigned*)(ws + kLlistOff);
  unsigned* Hlist = (unsigned*)(ws + kHlistOff);
  unsigned short* hashes = (unsigned short*)(ws + kHashOff);
  unsigned* lr = (unsigned*)(ws + kLrOff);
  unsigned short* feat_t = (unsigned short*)(ws + kFeatTOff);

  const dim3 blk(256);
  const int pblk = (kN / 4 + 255) / 256;  // 98 point-blocks per batch

  int chunkB = 0;
  for (int c = kB; c >= 1; c >>= 1) {
    if (ws_size >= wsNeed(c)) { chunkB = c; break; }
  }

  // fused: mean partials || zero out-grid || zero ws (maxbits..counts)
  zm_kernel<<<dim3(kMeanBlks + kOutZeroBlks + kWsZeroBlks), blk, 0, stream>>>(
      coords, dpart, (float4*)out, (float4*)(ws + kMaxOff));
  maxnorm_kernel<<<dim3(32, kB), blk, 0, stream>>>(coords, dpart, meanf, maxbits);

  if (chunkB) {
    hash_nc_kernel<<<dim3(pblk, kB), blk, 0, stream>>>(coords, meanf, maxbits, out_nc,
                                                       hashes, lr, counts);
    scan_reduce<<<dim3(256), blk, 0, stream>>>(counts, bsum3);
    scan_write<<<dim3(256), blk, 0, stream>>>(counts, bsum3, offsets, Llist, Hlist, nlh);

    for (int b0 = 0; b0 < kB; b0 += chunkB) {
      tr_kernel<<<dim3(kN / 32, chunkB), blk, 0, stream>>>(feat, hashes, lr, offsets,
                                                           feat_t, b0);
      gather_kernel<<<dim3(kLightBlks + kMaxHeavy), blk, 0, stream>>>(
          feat_t, offsets, Llist, Hlist, nlh, out, b0, chunkB);
    }
  } else {
    // fallback: direct atomics into final layout
    scatter_direct<<<dim3(pblk, kB), blk, 0, stream>>>(feat, coords, meanf, maxbits, out,
                                                       out_nc, counts);
    const size_t vec4 = kGridElems / 4;
    divide_inplace<<<dim3((unsigned)((vec4 + 255) / 256)), blk, 0, stream>>>(out, counts);
  }
}

// Round 15
// 166.833 us; speedup vs baseline: 2.1225x; 1.0784x over previous
//
#include <hip/hip_runtime.h>

namespace {
constexpr int kB = 8;
constexpr int kC = 64;
constexpr int kN = 100000;
constexpr int kR = 32;
constexpr int kR3 = kR * kR * kR;                     // 32768
constexpr size_t kGridElems = (size_t)kB * kC * kR3;  // 16,777,216
constexpr int kNV = kB * kR3;                         // 262144 voxel bins
constexpr int kNQ = kNV / 4;                          // 65536
constexpr unsigned kTh = 32;                          // light/heavy row threshold
constexpr int kMaxHeavy = kB * kN / (int)(kTh + 1) + 2;  // <= 24244
constexpr int kLightBlks = kNV / 16;                  // 16384

// ws layout (bytes)
constexpr size_t kDpartOff = 0;                                // 256 blk x 3 dbl = 6144
constexpr size_t kMeanfOff = 6144;                             // 24 floats
constexpr size_t kMaxOff = 6272;                               // 8 uints
constexpr size_t kNlhOff = 6336;                               // 2 uints
constexpr size_t kBsum3Off = 8192;                             // uint4[256] = 4 KB
constexpr size_t kCountsOff = 16384;                           // 1 MB
constexpr size_t kOffsetsOff = kCountsOff + (size_t)kNV * 4;   // (kNV+64) uints
constexpr size_t kLlistOff = kOffsetsOff + (size_t)(kNV + 64) * 4;  // u32 x kNV
constexpr size_t kHlistOff = kLlistOff + (size_t)kNV * 4;      // u32 x kNQ
constexpr size_t kHashOff = kHlistOff + (size_t)kNQ * 4;       // u16 x 800000
constexpr size_t kLrOff = kHashOff + (size_t)kB * kN * 2;      // u32 x 800000
constexpr size_t kFeatTOff = kLrOff + (size_t)kB * kN * 4;     // fp8 rows (64 B each)
inline size_t wsNeed(int chunkB) { return kFeatTOff + (size_t)chunkB * kN * kC; }
// fused zero+mean geometry
constexpr unsigned kMeanBlks = 256;  // 32 blocks x 8 batches
constexpr unsigned kOutZeroBlks = (unsigned)(kGridElems * 4 / 16 / 256);  // 16384
constexpr unsigned kWsZeroF4 = (unsigned)((kCountsOff + (size_t)kNV * 4 - kMaxOff) / 16);
constexpr unsigned kWsZeroBlks = (kWsZeroF4 + 255) / 256;  // covers maxbits..counts end
}  // namespace

__device__ __forceinline__ void f4add(float4& a, const float4& f) {
  a.x += f.x; a.y += f.y; a.z += f.z; a.w += f.w;
}

// ---------------- fp8 e4m3fn software encode/decode (RNE, FTZ) ---------------
__device__ __forceinline__ unsigned f2e4m3(float f) {
  const unsigned u = __float_as_uint(f);
  const unsigned s = (u >> 24) & 0x80u;
  int e = (int)((u >> 23) & 0xFFu) - 127;
  if (e < -6) return s;  // flush |f| < 2^-6 to signed zero (abs err <= 0.0156)
  unsigned m = u & 0x7FFFFFu;
  const unsigned mr = m + 0x7FFFFu + ((m >> 20) & 1u);
  if (mr & 0x800000u) {
    e += 1;
    m = 0;
  } else {
    m = mr;
  }
  return s | ((unsigned)(e + 7) << 3) | ((m >> 20) & 7u);
}
__device__ __forceinline__ float e4m3f(unsigned b8) {
  const unsigned E = (b8 >> 3) & 0xFu;
  const unsigned v = ((b8 & 0x80u) << 24) | ((E + 120u) << 23) | ((b8 & 7u) << 20);
  return (E == 0u) ? 0.0f : __uint_as_float(v);
}
__device__ __forceinline__ void q4add(float4& a, unsigned u) {
  a.x += e4m3f(u & 0xFFu);
  a.y += e4m3f((u >> 8) & 0xFFu);
  a.z += e4m3f((u >> 16) & 0xFFu);
  a.w += e4m3f(u >> 24);
}

// --- Kernel A' (fused): mean partials (256 blks) || zero out || zero ws ------
__global__ __launch_bounds__(256) void zm_kernel(const float* __restrict__ coords,
                                                 double* __restrict__ dpart,
                                                 float4* __restrict__ outz,
                                                 float4* __restrict__ wsz) {
  const unsigned bx = blockIdx.x;
  if (bx < kMeanBlks) {
    const int b = (int)(bx >> 5);
    const int xb = (int)(bx & 31);
    const float* cb = coords + (size_t)b * 3 * kN;
    double s0 = 0.0, s1 = 0.0, s2 = 0.0;
    for (int n = xb * 256 + (int)threadIdx.x; n < kN; n += 8192) {
      s0 += (double)cb[n];
      s1 += (double)cb[kN + n];
      s2 += (double)cb[2 * kN + n];
    }
    __shared__ double sh[3][256];
    sh[0][threadIdx.x] = s0;
    sh[1][threadIdx.x] = s1;
    sh[2][threadIdx.x] = s2;
    __syncthreads();
    for (int off = 128; off > 0; off >>= 1) {
      if (threadIdx.x < (unsigned)off) {
        sh[0][threadIdx.x] += sh[0][threadIdx.x + off];
        sh[1][threadIdx.x] += sh[1][threadIdx.x + off];
        sh[2][threadIdx.x] += sh[2][threadIdx.x + off];
      }
      __syncthreads();
    }
    if (threadIdx.x == 0) {
      dpart[(size_t)bx * 3 + 0] = sh[0][0];
      dpart[(size_t)bx * 3 + 1] = sh[1][0];
      dpart[(size_t)bx * 3 + 2] = sh[2][0];
    }
  } else if (bx < kMeanBlks + kOutZeroBlks) {
    outz[(size_t)(bx - kMeanBlks) * 256 + threadIdx.x] =
        make_float4(0.f, 0.f, 0.f, 0.f);
  } else {
    const unsigned i = (bx - kMeanBlks - kOutZeroBlks) * 256 + threadIdx.x;
    if (i < kWsZeroF4) wsz[i] = make_float4(0.f, 0.f, 0.f, 0.f);
  }
}

// -- Kernel B: mean from partials (fixed order) + max sq-norm (f32, no fma) ---
__global__ __launch_bounds__(256) void maxnorm_kernel(const float* __restrict__ coords,
                                                      const double* __restrict__ dpart,
                                                      float* __restrict__ meanf,
                                                      unsigned* __restrict__ maxbits) {
#pragma clang fp contract(off)
  const int b = blockIdx.y;
  __shared__ float m[3];
  if (threadIdx.x == 0) {
    double s0 = 0.0, s1 = 0.0, s2 = 0.0;
    for (int j = 0; j < 32; ++j) {
      s0 += dpart[(size_t)(b * 32 + j) * 3 + 0];
      s1 += dpart[(size_t)(b * 32 + j) * 3 + 1];
      s2 += dpart[(size_t)(b * 32 + j) * 3 + 2];
    }
    m[0] = (float)(s0 / (double)kN);
    m[1] = (float)(s1 / (double)kN);
    m[2] = (float)(s2 / (double)kN);
    if (blockIdx.x == 0) {
      meanf[b * 3 + 0] = m[0];
      meanf[b * 3 + 1] = m[1];
      meanf[b * 3 + 2] = m[2];
    }
  }
  __syncthreads();
  const float m0 = m[0], m1 = m[1], m2 = m[2];
  const int tid = blockIdx.x * 256 + threadIdx.x;
  const int stride = gridDim.x * 256;
  const float* cb = coords + (size_t)b * 3 * kN;
  float mx = 0.0f;
  for (int n = tid; n < kN; n += stride) {
    float x = cb[n] - m0;
    float y = cb[kN + n] - m1;
    float z = cb[2 * kN + n] - m2;
    float sx = x * x;
    float sy = y * y;
    float sz = z * z;
    float s = (sx + sy) + sz;  // match numpy's non-fused order
    mx = fmaxf(mx, s);
  }
  __shared__ float sh[256];
  sh[threadIdx.x] = mx;
  __syncthreads();
  for (int off = 128; off > 0; off >>= 1) {
    if (threadIdx.x < (unsigned)off)
      sh[threadIdx.x] = fmaxf(sh[threadIdx.x], sh[threadIdx.x + off]);
    __syncthreads();
  }
  if (threadIdx.x == 0) atomicMax(&maxbits[b], __float_as_uint(sh[0]));
}

// ---------- common per-point geometry: returns h[4], writes norm_coords ------
__device__ __forceinline__ void point_geom(const float* __restrict__ coords,
                                           const float* __restrict__ meanf,
                                           const unsigned* __restrict__ maxbits,
                                           float* __restrict__ out_nc, int b, int n0,
                                           int h[4]) {
#pragma clang fp contract(off)
  const float m0 = meanf[b * 3 + 0];
  const float m1 = meanf[b * 3 + 1];
  const float m2 = meanf[b * 3 + 2];
  const float scale = 2.0f * sqrtf(__uint_as_float(maxbits[b]));

  const float* cb = coords + (size_t)b * 3 * kN;
  const float4 cx = *(const float4*)(cb + n0);
  const float4 cy = *(const float4*)(cb + kN + n0);
  const float4 cz = *(const float4*)(cb + 2 * kN + n0);

  float xa[4] = {cx.x, cx.y, cx.z, cx.w};
  float ya[4] = {cy.x, cy.y, cy.z, cy.w};
  float za[4] = {cz.x, cz.y, cz.z, cz.w};
  float vx[4], vy[4], vz[4];
#pragma unroll
  for (int k = 0; k < 4; ++k) {
    float tx = (xa[k] - m0) / scale + 0.5f;
    float ty = (ya[k] - m1) / scale + 0.5f;
    float tz = (za[k] - m2) / scale + 0.5f;
    vx[k] = fminf(fmaxf(tx * 32.0f, 0.0f), 31.0f);
    vy[k] = fminf(fmaxf(ty * 32.0f, 0.0f), 31.0f);
    vz[k] = fminf(fmaxf(tz * 32.0f, 0.0f), 31.0f);
    int ix = (int)rintf(vx[k]);
    int iy = (int)rintf(vy[k]);
    int iz = (int)rintf(vz[k]);
    h[k] = ix * (kR * kR) + iy * kR + iz;
  }
  float* nb = out_nc + (size_t)b * 3 * kN;
  *(float4*)(nb + n0) = make_float4(vx[0], vx[1], vx[2], vx[3]);
  *(float4*)(nb + kN + n0) = make_float4(vy[0], vy[1], vy[2], vy[3]);
  *(float4*)(nb + 2 * kN + n0) = make_float4(vz[0], vz[1], vz[2], vz[3]);
}

// - Kernel C: hash + nc + count histogram + local rank (800k uint atomics) ----
__global__ __launch_bounds__(256) void hash_nc_kernel(
    const float* __restrict__ coords, const float* __restrict__ meanf,
    const unsigned* __restrict__ maxbits, float* __restrict__ out_nc,
    unsigned short* __restrict__ hashes, unsigned* __restrict__ lr,
    unsigned* __restrict__ counts) {
  const int b = blockIdx.y;
  const int n0 = (blockIdx.x * 256 + threadIdx.x) * 4;
  if (n0 >= kN) return;
  int h[4];
  point_geom(coords, meanf, maxbits, out_nc, b, n0, h);
  ushort4 h4;
  h4.x = (unsigned short)h[0];
  h4.y = (unsigned short)h[1];
  h4.z = (unsigned short)h[2];
  h4.w = (unsigned short)h[3];
  *(ushort4*)(hashes + (size_t)b * kN + n0) = h4;
  unsigned* cnt = counts + (size_t)b * kR3;
  uint4 l;
  l.x = atomicAdd(&cnt[h[0]], 1u);
  l.y = atomicAdd(&cnt[h[1]], 1u);
  l.z = atomicAdd(&cnt[h[2]], 1u);
  l.w = atomicAdd(&cnt[h[3]], 1u);
  *(uint4*)(lr + (size_t)b * kN + n0) = l;
}

// ------------- fused scan (2 kernels): offsets + light/heavy lists -----------
__global__ __launch_bounds__(256) void scan_reduce(const unsigned* __restrict__ counts,
                                                   uint4* __restrict__ bsum3) {
  __shared__ unsigned sht[256], shl[256], shh[256];
  const int t = threadIdx.x;
  const uint4 c = ((const uint4*)counts)[blockIdx.x * 256 + t];
  const unsigned cnt[4] = {c.x, c.y, c.z, c.w};
  unsigned tot = 0, lt = 0, ht = 0;
#pragma unroll
  for (int k = 0; k < 4; ++k) {
    tot += cnt[k];
    lt += (cnt[k] >= 1u && cnt[k] <= kTh) ? 1u : 0u;
    ht += (cnt[k] > kTh) ? 1u : 0u;
  }
  sht[t] = tot;
  shl[t] = lt;
  shh[t] = ht;
  __syncthreads();
  for (int off = 128; off > 0; off >>= 1) {
    if (t < off) {
      sht[t] += sht[t + off];
      shl[t] += shl[t + off];
      shh[t] += shh[t + off];
    }
    __syncthreads();
  }
  if (t == 0) bsum3[blockIdx.x] = make_uint4(sht[0], shl[0], shh[0], 0u);
}

__global__ __launch_bounds__(256) void scan_write(const unsigned* __restrict__ counts,
                                                  const uint4* __restrict__ bsum3,
                                                  unsigned* __restrict__ offsets,
                                                  unsigned* __restrict__ Llist,
                                                  unsigned* __restrict__ Hlist,
                                                  unsigned* __restrict__ nlh) {
  __shared__ unsigned sht[256], shl[256], shh[256];
  const int t = threadIdx.x;
  // phase 1: local scan of the 256 block totals for this block's exclusive base
  const uint4 bv = bsum3[t];
  sht[t] = bv.x;
  shl[t] = bv.y;
  shh[t] = bv.z;
  __syncthreads();
  for (int d = 1; d < 256; d <<= 1) {
    const unsigned xt = (t >= d) ? sht[t - d] : 0u;
    const unsigned xl = (t >= d) ? shl[t - d] : 0u;
    const unsigned xh = (t >= d) ? shh[t - d] : 0u;
    __syncthreads();
    sht[t] += xt;
    shl[t] += xl;
    shh[t] += xh;
    __syncthreads();
  }
  const unsigned bbt = (blockIdx.x > 0) ? sht[blockIdx.x - 1] : 0u;
  const unsigned bbl = (blockIdx.x > 0) ? shl[blockIdx.x - 1] : 0u;
  const unsigned bbh = (blockIdx.x > 0) ? shh[blockIdx.x - 1] : 0u;
  __syncthreads();
  // phase 2: in-block element scan
  const int gi = blockIdx.x * 256 + t;
  const int v0 = gi * 4;
  const uint4 c = ((const uint4*)counts)[gi];
  const unsigned cnt[4] = {c.x, c.y, c.z, c.w};
  unsigned lf[4], hf[4], tot = 0, lt = 0, ht = 0;
#pragma unroll
  for (int k = 0; k < 4; ++k) {
    lf[k] = (cnt[k] >= 1u && cnt[k] <= kTh) ? 1u : 0u;
    hf[k] = (cnt[k] > kTh) ? 1u : 0u;
    tot += cnt[k];
    lt += lf[k];
    ht += hf[k];
  }
  sht[t] = tot;
  shl[t] = lt;
  shh[t] = ht;
  __syncthreads();
  for (int d = 1; d < 256; d <<= 1) {
    const unsigned xt = (t >= d) ? sht[t - d] : 0u;
    const unsigned xl = (t >= d) ? shl[t - d] : 0u;
    const unsigned xh = (t >= d) ? shh[t - d] : 0u;
    __syncthreads();
    sht[t] += xt;
    shl[t] += xl;
    shh[t] += xh;
    __syncthreads();
  }
  const unsigned base = bbt + sht[t] - tot;
  uint4 o;
  o.x = base;
  o.y = o.x + cnt[0];
  o.z = o.y + cnt[1];
  o.w = o.z + cnt[2];
  ((uint4*)offsets)[gi] = o;
  if (gi == kNV / 4 - 1) offsets[kNV] = o.w + cnt[3];  // total = B*N
  unsigned lbase = bbl + shl[t] - lt;
  unsigned hbase = bbh + shh[t] - ht;
#pragma unroll
  for (int k = 0; k < 4; ++k) {
    if (lf[k]) Llist[lbase++] = (unsigned)(v0 + k);
    if (hf[k]) Hlist[hbase++] = (unsigned)(v0 + k);
  }
  if (blockIdx.x == 255 && t == 255) {
    nlh[0] = lbase;
    nlh[1] = hbase;
  }
}

// - Kernel F: transpose feat (B,C,N) -> SORTED fp8 rows feat_t[off+lr][c] -----
__global__ __launch_bounds__(256) void tr_kernel(const float* __restrict__ feat,
                                                 const unsigned short* __restrict__ hashes,
                                                 const unsigned* __restrict__ lr,
                                                 const unsigned* __restrict__ offsets,
                                                 unsigned char* __restrict__ feat_t,
                                                 int b0) {
  const int b2 = blockIdx.y;
  const int b = b0 + b2;
  const int n0 = blockIdx.x * 32;
  __shared__ float tile[64][33];
  __shared__ unsigned shr[32];
  if (threadIdx.x < 32) {
    const int n = n0 + threadIdx.x;
    const unsigned hh = hashes[(size_t)b * kN + n];
    const unsigned l = lr[(size_t)b * kN + n];
    shr[threadIdx.x] = offsets[(size_t)b * kR3 + hh] + l - (unsigned)b0 * (unsigned)kN;
  }
  const float* fb = feat + (size_t)b * kC * kN;
#pragma unroll
  for (int j = 0; j < 2; ++j) {
    const int idx = j * 256 + threadIdx.x;  // 0..511
    const int c = idx >> 3;
    const int q = idx & 7;
    const float4 v = *(const float4*)(fb + (size_t)c * kN + n0 + q * 4);
    tile[c][q * 4 + 0] = v.x;
    tile[c][q * 4 + 1] = v.y;
    tile[c][q * 4 + 2] = v.z;
    tile[c][q * 4 + 3] = v.w;
  }
  __syncthreads();
#pragma unroll
  for (int j = 0; j < 2; ++j) {
    const int idx = j * 256 + threadIdx.x;  // 0..511
    const int n = idx >> 4;
    const int cq = idx & 15;
    const unsigned w = f2e4m3(tile[cq * 4 + 0][n]) |
                       (f2e4m3(tile[cq * 4 + 1][n]) << 8) |
                       (f2e4m3(tile[cq * 4 + 2][n]) << 16) |
                       (f2e4m3(tile[cq * 4 + 3][n]) << 24);
    const size_t row = (size_t)shr[n];
    *(unsigned*)(feat_t + row * kC + cq * 4) = w;
  }
}

// ---- Kernel G (fused): light blocks [0,kLightBlks), heavy blocks after ------
__global__ __launch_bounds__(256) void gather_kernel(const unsigned char* __restrict__ feat_t,
                                                     const unsigned* __restrict__ offsets,
                                                     const unsigned* __restrict__ Llist,
                                                     const unsigned* __restrict__ Hlist,
                                                     const unsigned* __restrict__ nlh,
                                                     float* __restrict__ out, int b0,
                                                     int chunkB) {
  const unsigned rb = (unsigned)b0 * (unsigned)kN;
  const unsigned vlo = (unsigned)b0 * (unsigned)kR3;
  const unsigned vhi = (unsigned)(b0 + chunkB) * (unsigned)kR3;

  if (blockIdx.x < (unsigned)kLightBlks) {
    // ---- light path: wave handles 4 list entries ----
    const unsigned nl = nlh[0];
    const int wid = blockIdx.x * 4 + (threadIdx.x >> 6);
    const int lane = threadIdx.x & 63;
    const int p = lane >> 4;   // list slot 0..3
    const int cq = lane & 15;  // channel quad
    const unsigned i0 = (unsigned)wid * 4;
    if (i0 >= nl) return;
    const unsigned ip = i0 + (unsigned)p;
    bool act = ip < nl;
    const unsigned v = Llist[act ? ip : i0];
    act = act && (v >= vlo) && (v < vhi);
    const unsigned s = offsets[v];
    unsigned e = offsets[v + 1];
    if (!act) e = s;
    const unsigned* ft = (const unsigned*)feat_t + cq;  // row stride = 16 uints
    float4 acc = make_float4(0.f, 0.f, 0.f, 0.f);
    unsigned r = s;
    for (; r + 2 <= e; r += 2) {
      const unsigned u0 = ft[(size_t)(r - rb) * 16];
      const unsigned u1 = ft[(size_t)(r + 1 - rb) * 16];
      q4add(acc, u0);
      q4add(acc, u1);
    }
    if (r < e) {
      q4add(acc, ft[(size_t)(r - rb) * 16]);
    }
    if (act) {
      const float k = (float)(e - s);
      const int b = (int)(v >> 15);
      const int h = (int)(v & (kR3 - 1));
      float* ob = out + ((size_t)b * kC + cq * 4) * kR3 + h;
      ob[0] = acc.x / k;
      ob[(size_t)kR3] = acc.y / k;
      ob[(size_t)2 * kR3] = acc.z / k;
      ob[(size_t)3 * kR3] = acc.w / k;
    }
  } else {
    // ---- heavy path: one 256-thread block per voxel ----
    const unsigned hb = blockIdx.x - (unsigned)kLightBlks;
    const unsigned nh = nlh[1];
    if (hb >= nh) return;
    const unsigned v = Hlist[hb];
    if (v < vlo || v >= vhi) return;
    const unsigned s = offsets[v];
    const unsigned e = offsets[v + 1];
    const int slot = threadIdx.x >> 4;  // row slot 0..15
    const int cq = threadIdx.x & 15;    // channel quad
    float4 acc = make_float4(0.f, 0.f, 0.f, 0.f);
    for (unsigned r = s + (unsigned)slot; r < e; r += 16) {
      const unsigned u = *((const unsigned*)(feat_t + (size_t)(r - rb) * kC) + cq);
      q4add(acc, u);
    }
    __shared__ float sh[16][64];
    sh[slot][cq * 4 + 0] = acc.x;
    sh[slot][cq * 4 + 1] = acc.y;
    sh[slot][cq * 4 + 2] = acc.z;
    sh[slot][cq * 4 + 3] = acc.w;
    __syncthreads();
    if (threadIdx.x < 64) {
      const int c = threadIdx.x;
      float t = 0.f;
#pragma unroll
      for (int k = 0; k < 16; ++k) t += sh[k][c];
      const int b = (int)(v >> 15);
      const int h = (int)(v & (kR3 - 1));
      out[((size_t)b * kC + c) * kR3 + h] = t / (float)(e - s);
    }
  }
}

// --------------- Fallback: direct atomics into out (b,c,h) -------------------
__global__ __launch_bounds__(256) void scatter_direct(
    const float* __restrict__ feat, const float* __restrict__ coords,
    const float* __restrict__ meanf, const unsigned* __restrict__ maxbits,
    float* __restrict__ gridsum, float* __restrict__ out_nc,
    unsigned* __restrict__ counts) {
  const int b = blockIdx.y;
  const int n0 = (blockIdx.x * 256 + threadIdx.x) * 4;
  if (n0 >= kN) return;
  int h[4];
  point_geom(coords, meanf, maxbits, out_nc, b, n0, h);
  unsigned* cnt = counts + (size_t)b * kR3;
  atomicAdd(&cnt[h[0]], 1u);
  atomicAdd(&cnt[h[1]], 1u);
  atomicAdd(&cnt[h[2]], 1u);
  atomicAdd(&cnt[h[3]], 1u);
  const float* fb = feat + (size_t)b * kC * kN + n0;
  float* gb = gridsum + (size_t)b * kC * kR3;
#pragma unroll 8
  for (int c = 0; c < kC; ++c) {
    const float4 f = *(const float4*)(fb + (size_t)c * kN);
    float* g = gb + (size_t)c * kR3;
    unsafeAtomicAdd(g + h[0], f.x);
    unsafeAtomicAdd(g + h[1], f.y);
    unsafeAtomicAdd(g + h[2], f.z);
    unsafeAtomicAdd(g + h[3], f.w);
  }
}

__global__ __launch_bounds__(256) void divide_inplace(float* __restrict__ grid,
                                                      const unsigned* __restrict__ counts) {
  const size_t e = ((size_t)blockIdx.x * blockDim.x + threadIdx.x) * 4;
  if (e >= kGridElems) return;
  const int h = (int)(e & (size_t)(kR3 - 1));
  const int b = (int)(e >> 21);
  const uint4 cnt = *(const uint4*)(counts + (size_t)b * kR3 + h);
  float4 g = *(float4*)(grid + e);
  g.x = g.x / (float)(cnt.x > 1u ? cnt.x : 1u);
  g.y = g.y / (float)(cnt.y > 1u ? cnt.y : 1u);
  g.z = g.z / (float)(cnt.z > 1u ? cnt.z : 1u);
  g.w = g.w / (float)(cnt.w > 1u ? cnt.w : 1u);
  *(float4*)(grid + e) = g;
}

extern "C" void kernel_launch(void* const* d_in, const int* in_sizes, int n_in,
                              void* d_out, int out_size, void* d_ws, size_t ws_size,
                              hipStream_t stream) {
  const float* feat = (const float*)d_in[0];    // (8, 64, 100000)
  const float* coords = (const float*)d_in[1];  // (8, 3, 100000)
  float* out = (float*)d_out;
  float* out_nc = out + kGridElems;  // (8, 3, 100000)

  char* ws = (char*)d_ws;
  double* dpart = (double*)(ws + kDpartOff);
  float* meanf = (float*)(ws + kMeanfOff);
  unsigned* maxbits = (unsigned*)(ws + kMaxOff);
  unsigned* nlh = (unsigned*)(ws + kNlhOff);
  uint4* bsum3 = (uint4*)(ws + kBsum3Off);
  unsigned* counts = (unsigned*)(ws + kCountsOff);
  unsigned* offsets = (unsigned*)(ws + kOffsetsOff);
  unsigned* Llist = (unsigned*)(ws + kLlistOff);
  unsigned* Hlist = (unsigned*)(ws + kHlistOff);
  unsigned short* hashes = (unsigned short*)(ws + kHashOff);
  unsigned* lr = (unsigned*)(ws + kLrOff);
  unsigned char* feat_t = (unsigned char*)(ws + kFeatTOff);

  const dim3 blk(256);
  const int pblk = (kN / 4 + 255) / 256;  // 98 point-blocks per batch

  int chunkB = 0;
  for (int c = kB; c >= 1; c >>= 1) {
    if (ws_size >= wsNeed(c)) { chunkB = c; break; }
  }

  // fused: mean partials || zero out-grid || zero ws (maxbits..counts)
  zm_kernel<<<dim3(kMeanBlks + kOutZeroBlks + kWsZeroBlks), blk, 0, stream>>>(
      coords, dpart, (float4*)out, (float4*)(ws + kMaxOff));
  maxnorm_kernel<<<dim3(64, kB), blk, 0, stream>>>(coords, dpart, meanf, maxbits);

  if (chunkB) {
    hash_nc_kernel<<<dim3(pblk, kB), blk, 0, stream>>>(coords, meanf, maxbits, out_nc,
                                                       hashes, lr, counts);
    scan_reduce<<<dim3(256), blk, 0, stream>>>(counts, bsum3);
    scan_write<<<dim3(256), blk, 0, stream>>>(counts, bsum3, offsets, Llist, Hlist, nlh);

    for (int b0 = 0; b0 < kB; b0 += chunkB) {
      tr_kernel<<<dim3(kN / 32, chunkB), blk, 0, stream>>>(feat, hashes, lr, offsets,
                                                           feat_t, b0);
      gather_kernel<<<dim3(kLightBlks + kMaxHeavy), blk, 0, stream>>>(
          feat_t, offsets, Llist, Hlist, nlh, out, b0, chunkB);
    }
  } else {
    // fallback: direct atomics into final layout
    scatter_direct<<<dim3(pblk, kB), blk, 0, stream>>>(feat, coords, meanf, maxbits, out,
                                                       out_nc, counts);
    const size_t vec4 = kGridElems / 4;
    divide_inplace<<<dim3((unsigned)((vec4 + 255) / 256)), blk, 0, stream>>>(out, counts);
  }
}